// Round 5
// baseline (1029.179 us; speedup 1.0000x reference)
//
#include <hip/hip_runtime.h>
#include <cstdint>

#define VOC   32768
#define DIM   512
#define TOPK  64
#define BATCH 4096

#define KSIG     2.45f
#define EPS_SEL  0.012f
#define CAND_CAP 512
#define RES_CAP  256
#define FCAP     1024

typedef unsigned short u16;
typedef __attribute__((ext_vector_type(8))) short bf16x8;
typedef __attribute__((ext_vector_type(4))) float f32x4;

// ---- bf16 helpers (RNE) ----------------------------------------------------
__device__ __forceinline__ u16 f2bf(float f) {
    unsigned u = __float_as_uint(f);
    unsigned r = (u + 0x7FFFu + ((u >> 16) & 1u)) >> 16;
    return (u16)r;
}
__device__ __forceinline__ float bf2f(u16 h) {
    return __uint_as_float(((unsigned)h) << 16);
}
// 16-bit sortable key <-> bf16
__device__ __forceinline__ unsigned enc16(u16 h) {
    return (h & 0x8000u) ? (unsigned)((u16)~h) : (unsigned)(h | 0x8000u);
}
__device__ __forceinline__ float dec16(unsigned s16) {
    u16 h = (s16 & 0x8000u) ? (u16)(s16 ^ 0x8000u) : (u16)(~s16);
    return bf2f(h);
}

// ---- async global->LDS 16B -------------------------------------------------
__device__ __forceinline__ void async16(const void* g, void* l) {
    __builtin_amdgcn_global_load_lds(
        (const __attribute__((address_space(1))) void*)g,
        (__attribute__((address_space(3))) void*)l, 16, 0, 0);
}

// ---------------------------------------------------------------------------
// fp32 tiled GEMM + optional per-k-tile fp64 flush (round-1, known good).
// ---------------------------------------------------------------------------
template <bool BT, bool F64ACC>
__global__ __launch_bounds__(256)
void gemm_kernel(const float* __restrict__ A, const float* __restrict__ B,
                 const float* __restrict__ bias, float* __restrict__ C,
                 int M, int N, int K)
{
    const int BM = 128, BN = 64, KS = 16;
    __shared__ float As[KS][BM + 4];
    __shared__ float Bs[KS][BN];

    const int tid = threadIdx.x;
    const int m0 = blockIdx.y * BM;
    const int n0 = blockIdx.x * BN;
    const int ty = tid >> 4;
    const int tx = tid & 15;

    float acc[8][4];
    double acc64[8][4];
#pragma unroll
    for (int i = 0; i < 8; i++)
#pragma unroll
        for (int j = 0; j < 4; j++) { acc[i][j] = 0.f; if (F64ACC) acc64[i][j] = 0.0; }

    for (int kt = 0; kt < K; kt += KS) {
#pragma unroll
        for (int s = 0; s < 2; s++) {
            int c = tid + s * 256;
            int row = c >> 2;
            int kq  = c & 3;
            const float4 av = *(const float4*)(A + (size_t)(m0 + row) * K + kt + kq * 4);
            As[kq * 4 + 0][row] = av.x;
            As[kq * 4 + 1][row] = av.y;
            As[kq * 4 + 2][row] = av.z;
            As[kq * 4 + 3][row] = av.w;
        }
        if (!BT) {
            int krow = tid >> 4;
            int nq   = tid & 15;
            const float4 bv = *(const float4*)(B + (size_t)(kt + krow) * N + n0 + nq * 4);
            *(float4*)&Bs[krow][nq * 4] = bv;
        } else {
            int nrow = tid >> 2;
            int kq   = tid & 3;
            const float4 bv = *(const float4*)(B + (size_t)(n0 + nrow) * K + kt + kq * 4);
            Bs[kq * 4 + 0][nrow] = bv.x;
            Bs[kq * 4 + 1][nrow] = bv.y;
            Bs[kq * 4 + 2][nrow] = bv.z;
            Bs[kq * 4 + 3][nrow] = bv.w;
        }
        __syncthreads();

#pragma unroll
        for (int kk = 0; kk < KS; kk++) {
            float4 a0 = *(const float4*)&As[kk][ty * 8];
            float4 a1 = *(const float4*)&As[kk][ty * 8 + 4];
            float4 b  = *(const float4*)&Bs[kk][tx * 4];
            float av[8] = {a0.x, a0.y, a0.z, a0.w, a1.x, a1.y, a1.z, a1.w};
            float bv[4] = {b.x, b.y, b.z, b.w};
#pragma unroll
            for (int i = 0; i < 8; i++)
#pragma unroll
                for (int j = 0; j < 4; j++)
                    acc[i][j] += av[i] * bv[j];
        }
        __syncthreads();
        if (F64ACC) {
#pragma unroll
            for (int i = 0; i < 8; i++)
#pragma unroll
                for (int j = 0; j < 4; j++) { acc64[i][j] += (double)acc[i][j]; acc[i][j] = 0.f; }
        }
    }

    float4 bb = make_float4(0.f, 0.f, 0.f, 0.f);
    if (bias) bb = *(const float4*)(bias + n0 + tx * 4);
#pragma unroll
    for (int i = 0; i < 8; i++) {
        float4 o;
        float r0 = F64ACC ? (float)acc64[i][0] : acc[i][0];
        float r1 = F64ACC ? (float)acc64[i][1] : acc[i][1];
        float r2 = F64ACC ? (float)acc64[i][2] : acc[i][2];
        float r3 = F64ACC ? (float)acc64[i][3] : acc[i][3];
        o.x = r0 + bb.x; o.y = r1 + bb.y; o.z = r2 + bb.z; o.w = r3 + bb.w;
        *(float4*)(C + (size_t)(m0 + ty * 8 + i) * N + n0 + tx * 4) = o;
    }
}

// ---------------------------------------------------------------------------
__global__ void bias_fold(const float* __restrict__ bq, const float* __restrict__ Wk,
                          float* __restrict__ bqk)
{
    int j = blockIdx.x * 256 + threadIdx.x;
    if (j >= DIM) return;
    double s = 0.0;
    const float* wr = Wk + (size_t)j * DIM;
    for (int d = 0; d < DIM; d++) s += (double)bq[d] * (double)wr[d];
    bqk[j] = (float)s;
}

// ---------------------------------------------------------------------------
__global__ void zero_ws(unsigned* __restrict__ p, int n)
{
    int i = blockIdx.x * 256 + threadIdx.x;
    if (i < n) p[i] = 0u;
}

// ---------------------------------------------------------------------------
// Column sums of codebook (for mu_row = q2 . cbar/V).
// ---------------------------------------------------------------------------
__global__ __launch_bounds__(256)
void cbar_accum(const float* __restrict__ cb, float* __restrict__ cbarsum)
{
    const int tid = threadIdx.x;
    const int r0 = blockIdx.x * 512;
    float s0 = 0.f, s1 = 0.f;
    for (int r = 0; r < 512; r++) {
        const float* rp = cb + (size_t)(r0 + r) * DIM;
        s0 += rp[tid];
        s1 += rp[tid + 256];
    }
    atomicAdd(&cbarsum[tid], s0);
    atomicAdd(&cbarsum[tid + 256], s1);
}

// ---------------------------------------------------------------------------
// Per-row analytic threshold: t = mu + KSIG*sigma, sigma = ||q2_row||/sqrt(1536)
// (codebook iid U(+-1/sqrt(512)) => per-coord var = 1/1536).
// One wave per row.
// ---------------------------------------------------------------------------
__global__ __launch_bounds__(256)
void rowstats(const float* __restrict__ q2, const float* __restrict__ cbarsum,
              float* __restrict__ trow, float* __restrict__ sigrow)
{
    const int tid = threadIdx.x, lane = tid & 63, wave = tid >> 6;
    const int row = blockIdx.x * 4 + wave;
    const float* qp = q2 + (size_t)row * DIM + lane * 8;
    float4 a0 = *(const float4*)qp, a1 = *(const float4*)(qp + 4);
    const float* cp = cbarsum + lane * 8;
    float4 c0 = *(const float4*)cp, c1 = *(const float4*)(cp + 4);
    float mu = a0.x*c0.x + a0.y*c0.y + a0.z*c0.z + a0.w*c0.w
             + a1.x*c1.x + a1.y*c1.y + a1.z*c1.z + a1.w*c1.w;
    float nr = a0.x*a0.x + a0.y*a0.y + a0.z*a0.z + a0.w*a0.w
             + a1.x*a1.x + a1.y*a1.y + a1.z*a1.z + a1.w*a1.w;
#pragma unroll
    for (int off = 32; off > 0; off >>= 1) {
        mu += __shfl_down(mu, off);
        nr += __shfl_down(nr, off);
    }
    if (lane == 0) {
        mu *= (1.f / VOC);
        float sig = sqrtf(nr * (1.f / 1536.f));
        trow[row] = mu + KSIG * sig;
        sigrow[row] = sig;
    }
}

// ---------------------------------------------------------------------------
// Pack fp32 [R x 512] -> MFMA operand layout pk[ks][ch][R][8] bf16.
// ---------------------------------------------------------------------------
__global__ __launch_bounds__(256)
void pack_rows(const float* __restrict__ src, u16* __restrict__ hi,
               int R, int log2R)
{
    int idx = blockIdx.x * 256 + threadIdx.x;      // R*64 total
    int c8  = idx >> log2R;
    int row = idx & (R - 1);
    const float* sp = src + (size_t)row * DIM + c8 * 8;
    float xv[8];
    *(float4*)&xv[0] = *(const float4*)sp;
    *(float4*)&xv[4] = *(const float4*)(sp + 4);
    int ks = c8 >> 2, ch = c8 & 3;
    size_t ob = ((size_t)(ks * 4 + ch) * R + row) * 8;
    u16 h[8];
#pragma unroll
    for (int j = 0; j < 8; j++) h[j] = f2bf(xv[j]);
    *(uint4*)(hi + ob) = *(const uint4*)h;
}

// ---------------------------------------------------------------------------
// Fused dots GEMM: q2h[4096x512] @ cbh^T[32768x512] in bf16 MFMA; epilogue
// appends candidates (val >= trow[row]) as (bf16-sortkey<<16 | idx) into
// per-row capped lists. dots never hits memory.
// ---------------------------------------------------------------------------
__global__ __launch_bounds__(256, 2)
void mfma_dots(const u16* __restrict__ Ah, const u16* __restrict__ Bh,
               const float* __restrict__ trow, unsigned* __restrict__ candBuf,
               unsigned* __restrict__ counters)
{
    __shared__ u16 lds[2 * 4096];

    const int tid  = threadIdx.x;
    const int lane = tid & 63;
    const int wave = tid >> 6;
    const int wm = wave >> 1, wn = wave & 1;
    const int m0 = blockIdx.y * 128, n0 = blockIdx.x * 128;
    const int lr = lane & 15;
    const int q  = lane >> 4;

    f32x4 acc[4][4] = {};

    for (int ks = 0; ks < 16; ks++) {
        const int a = wave >> 1;                    // 0: A (q2h), 1: B (cbh)
        const u16* src = a ? Bh : Ah;
        const int rb = a ? n0 : m0;
        const size_t R = a ? (size_t)VOC : (size_t)BATCH;
#pragma unroll
        for (int s = 0; s < 4; s++) {
            int i = (wave & 1) * 4 + s;
            const u16* gp = src + ((size_t)(ks * 4 + (i >> 1)) * R + rb + (i & 1) * 64 + lane) * 8;
            async16(gp, &lds[a * 4096 + i * 512 + lane * 8]);
        }
        __syncthreads();

        bf16x8 ah[4];
#pragma unroll
        for (int mt = 0; mt < 4; mt++)
            ah[mt] = *(const bf16x8*)&lds[0 * 4096 + q * 1024 + (wm * 64 + mt * 16 + lr) * 8];
#pragma unroll
        for (int nt = 0; nt < 4; nt++) {
            bf16x8 bh = *(const bf16x8*)&lds[1 * 4096 + q * 1024 + (wn * 64 + nt * 16 + lr) * 8];
#pragma unroll
            for (int mt = 0; mt < 4; mt++)
                acc[mt][nt] = __builtin_amdgcn_mfma_f32_16x16x32_bf16(ah[mt], bh, acc[mt][nt], 0, 0, 0);
        }
        __syncthreads();
    }

    // epilogue: threshold-append candidates
#pragma unroll
    for (int mt = 0; mt < 4; mt++) {
#pragma unroll
        for (int r = 0; r < 4; r++) {
            int rowg = m0 + wm * 64 + mt * 16 + q * 4 + r;
            float tr = trow[rowg];
#pragma unroll
            for (int nt = 0; nt < 4; nt++) {
                float val = acc[mt][nt][r];
                if (val >= tr) {
                    unsigned slot = atomicAdd(&counters[rowg], 1u);
                    if (slot < CAND_CAP) {
                        unsigned s16 = enc16(f2bf(val));
                        candBuf[(size_t)rowg * CAND_CAP + slot] =
                            (s16 << 16) | (unsigned)(n0 + wn * 64 + nt * 16 + lr);
                    }
                }
            }
        }
    }
}

// ---------------------------------------------------------------------------
// Select v4: sort candidates by approx -> verify t <= a64 - 2*EPS (proof of
// top-64 coverage) -> fp64 rescue of band (wave per candidate, coalesced) ->
// exact sort -> thresh (ties kept) -> softmax -> y_row = sum w_i * cb[idx_i].
// Any anomaly sets flags[row] for the exact fallback kernel.
// ---------------------------------------------------------------------------
__global__ __launch_bounds__(256)
void select4(const unsigned* __restrict__ candBuf, const unsigned* __restrict__ counters,
             const float* __restrict__ trow, const float* __restrict__ q2,
             const float* __restrict__ codebook, float* __restrict__ y,
             unsigned* __restrict__ flags)
{
    __shared__ unsigned recs[CAND_CAP];
    __shared__ unsigned long long keys[RES_CAP];
    __shared__ float q2s[DIM];
    __shared__ float wArr[RES_CAP];
    __shared__ float redf[256];
    __shared__ unsigned redu[256];
    __shared__ unsigned s_R;

    const int tid  = threadIdx.x;
    const int lane = tid & 63;
    const int wave = tid >> 6;
    const int row  = blockIdx.x;

    const unsigned cnt = counters[row];
    if (cnt < TOPK || cnt > CAND_CAP) {
        if (tid == 0) flags[row] = 1u;
        return;
    }
    for (int i = tid; i < DIM; i += 256) q2s[i] = q2[(size_t)row * DIM + i];
    for (int i = tid; i < CAND_CAP; i += 256)
        recs[i] = (i < (int)cnt) ? candBuf[(size_t)row * CAND_CAP + i] : 0u;
    if (tid == 0) s_R = 0;
    __syncthreads();

    // bitonic sort 512 u32 DESCENDING (sortkey in high 16 bits; pads=0 last)
    for (int k = 2; k <= CAND_CAP; k <<= 1) {
        for (int j = k >> 1; j > 0; j >>= 1) {
#pragma unroll
            for (int e = 0; e < 2; e++) {
                int i = tid + e * 256;
                int ixj = i ^ j;
                if (ixj > i) {
                    unsigned a = recs[i], b = recs[ixj];
                    if (((i & k) == 0) ? (a < b) : (a > b)) { recs[i] = b; recs[ixj] = a; }
                }
            }
            __syncthreads();
        }
    }

    // verify coverage: t <= a64 - 2*EPS  (else fallback)
    const float a64  = dec16(recs[TOPK - 1] >> 16);
    const float band = a64 - 2.f * EPS_SEL;
    if (trow[row] > band) {
        if (tid == 0) flags[row] = 1u;
        return;
    }

    // R = prefix length with approx >= band
#pragma unroll
    for (int e = 0; e < 2; e++) {
        int i = tid + e * 256;
        if (i < (int)cnt && dec16(recs[i] >> 16) >= band) atomicAdd(&s_R, 1u);
    }
    __syncthreads();
    const int R = (int)s_R;
    if (R > RES_CAP) {
        if (tid == 0) flags[row] = 1u;
        return;
    }

    // fp64 rescue: wave per candidate, coalesced codebook reads
    for (int c = wave; c < R; c += 4) {
        unsigned idx = recs[c] & 0xFFFFu;
        const float* cb = codebook + (size_t)idx * DIM + lane * 8;
        float4 c0 = *(const float4*)cb, c1 = *(const float4*)(cb + 4);
        const float* qp = &q2s[lane * 8];
        float4 a0 = *(const float4*)qp, a1 = *(const float4*)(qp + 4);
        double s = (double)a0.x * c0.x + (double)a0.y * c0.y
                 + (double)a0.z * c0.z + (double)a0.w * c0.w
                 + (double)a1.x * c1.x + (double)a1.y * c1.y
                 + (double)a1.z * c1.z + (double)a1.w * c1.w;
#pragma unroll
        for (int off = 32; off > 0; off >>= 1) s += __shfl_down(s, off);
        if (lane == 0) {
            float val = (float)s;
            unsigned b = __float_as_uint(val);
            unsigned sk = (b & 0x80000000u) ? ~b : (b | 0x80000000u);
            keys[c] = ((unsigned long long)(~sk) << 32) | idx;
        }
    }
    if (tid >= R && tid < RES_CAP) keys[tid] = ~0ULL;
    __syncthreads();

    // bitonic sort 256 u64 ascending (= descending by exact value)
    for (int k = 2; k <= RES_CAP; k <<= 1) {
        for (int j = k >> 1; j > 0; j >>= 1) {
            int ixj = tid ^ j;
            if (ixj > tid) {
                unsigned long long a = keys[tid], b2 = keys[ixj];
                if (((tid & k) == 0) ? (a > b2) : (a < b2)) { keys[tid] = b2; keys[ixj] = a; }
            }
            __syncthreads();
        }
    }

    // thresh = exact 64th largest; keep all >= thresh; softmax
    const unsigned threshInv = (unsigned)(keys[TOPK - 1] >> 32);
    unsigned sk0 = ~(unsigned)(keys[0] >> 32);
    const float vmax = __uint_as_float((sk0 & 0x80000000u) ? (sk0 & 0x7FFFFFFFu) : ~sk0);

    unsigned hi = (unsigned)(keys[tid] >> 32);
    bool sel = (hi <= threshInv);
    unsigned sk = ~hi;
    float val = __uint_as_float((sk & 0x80000000u) ? (sk & 0x7FFFFFFFu) : ~sk);
    float w = sel ? expf(val - vmax) : 0.f;
    wArr[tid] = w;
    redf[tid] = w;
    redu[tid] = sel ? 1u : 0u;
    __syncthreads();
    for (int s = 128; s > 0; s >>= 1) {
        if (tid < s) { redf[tid] += redf[tid + s]; redu[tid] += redu[tid + s]; }
        __syncthreads();
    }
    const float invZ = 1.0f / redf[0];
    const int selCount = (int)redu[0];        // sorted => selected is a prefix

    // y_row = sum_i w_i * codebook[idx_i, :]   (out = y @ Wv + bv later)
    for (int d = tid; d < DIM; d += 256) {
        float acc = 0.f;
        for (int i = 0; i < selCount; i++) {
            unsigned idx = (unsigned)(keys[i] & 0xFFFFFFFFu);
            acc += wArr[i] * codebook[(size_t)idx * DIM + d];
        }
        y[(size_t)row * DIM + d] = acc * invZ;
    }
}

// ---------------------------------------------------------------------------
// Exact fallback for flagged rows (expected: none). Recomputes the row's dots
// in fp64->fp32, collects all >= tf (iterating tf until 64 <= cnt <= FCAP),
// exact sort, thresh, softmax, y. Launched always; exits fast when clean.
// ---------------------------------------------------------------------------
__global__ __launch_bounds__(256)
void fallback_row(const unsigned* __restrict__ flags, const float* __restrict__ q2,
                  const float* __restrict__ codebook, const float* __restrict__ trow,
                  const float* __restrict__ sigrow, float* __restrict__ y)
{
    const int row = blockIdx.x;
    if (!flags[row]) return;

    __shared__ float q2s[DIM];
    __shared__ unsigned long long keys[FCAP];
    __shared__ float wArr[FCAP];
    __shared__ float redf[256];
    __shared__ unsigned redu[256];
    __shared__ unsigned s_cnt;

    const int tid = threadIdx.x;
    for (int i = tid; i < DIM; i += 256) q2s[i] = q2[(size_t)row * DIM + i];
    const float sig = sigrow[row];
    float tf = trow[row] - 0.35f * sig;
    unsigned cnt = 0;

    for (int it = 0; it < 16; it++) {
        if (tid == 0) s_cnt = 0;
        __syncthreads();
        for (int i = tid; i < VOC; i += 256) {
            const float* cb = codebook + (size_t)i * DIM;
            double s = 0.0;
            for (int d = 0; d < DIM; d += 4) {
                float4 c4 = *(const float4*)(cb + d);
                s += (double)q2s[d + 0] * (double)c4.x + (double)q2s[d + 1] * (double)c4.y
                   + (double)q2s[d + 2] * (double)c4.z + (double)q2s[d + 3] * (double)c4.w;
            }
            float v = (float)s;
            if (v >= tf) {
                unsigned p = atomicAdd(&s_cnt, 1u);
                if (p < FCAP) {
                    unsigned b = __float_as_uint(v);
                    unsigned sk = (b & 0x80000000u) ? ~b : (b | 0x80000000u);
                    keys[p] = ((unsigned long long)(~sk) << 32) | (unsigned)i;
                }
            }
        }
        __syncthreads();
        cnt = s_cnt;
        if (cnt > FCAP)      { tf += 0.15f * sig; continue; }
        if (cnt < TOPK)      { tf -= 0.35f * sig; continue; }
        break;
    }
    if (cnt > FCAP) cnt = FCAP;
    for (int i = tid; i < FCAP; i += 256)
        if (i >= (int)cnt) keys[i] = ~0ULL;
    __syncthreads();

    // bitonic sort 1024 u64 ascending, 4 elems/thread
    for (int k = 2; k <= FCAP; k <<= 1) {
        for (int j = k >> 1; j > 0; j >>= 1) {
#pragma unroll
            for (int e = 0; e < 4; e++) {
                int i = tid + e * 256;
                int ixj = i ^ j;
                if (ixj > i) {
                    unsigned long long a = keys[i], b = keys[ixj];
                    if (((i & k) == 0) ? (a > b) : (a < b)) { keys[i] = b; keys[ixj] = a; }
                }
            }
            __syncthreads();
        }
    }

    const unsigned threshInv = (unsigned)(keys[TOPK - 1] >> 32);
    unsigned sk0 = ~(unsigned)(keys[0] >> 32);
    const float vmax = __uint_as_float((sk0 & 0x80000000u) ? (sk0 & 0x7FFFFFFFu) : ~sk0);

    float lsum = 0.f; unsigned lcnt = 0;
    for (int i = tid; i < FCAP; i += 256) {
        unsigned hi = (unsigned)(keys[i] >> 32);
        bool sel = (hi <= threshInv);
        unsigned sk = ~hi;
        float v = __uint_as_float((sk & 0x80000000u) ? (sk & 0x7FFFFFFFu) : ~sk);
        float w = sel ? expf(v - vmax) : 0.f;
        wArr[i] = w;
        lsum += w; lcnt += sel ? 1u : 0u;
    }
    redf[tid] = lsum; redu[tid] = lcnt;
    __syncthreads();
    for (int s = 128; s > 0; s >>= 1) {
        if (tid < s) { redf[tid] += redf[tid + s]; redu[tid] += redu[tid + s]; }
        __syncthreads();
    }
    const float invZ = 1.f / redf[0];
    const int selCount = (int)redu[0];

    for (int d = tid; d < DIM; d += 256) {
        float acc = 0.f;
        for (int i = 0; i < selCount; i++) {
            unsigned idx = (unsigned)(keys[i] & 0xFFFFFFFFu);
            acc += wArr[i] * codebook[(size_t)idx * DIM + d];
        }
        y[(size_t)row * DIM + d] = acc * invZ;
    }
}

// ---------------------------------------------------------------------------
extern "C" void kernel_launch(void* const* d_in, const int* in_sizes, int n_in,
                              void* d_out, int out_size, void* d_ws, size_t ws_size,
                              hipStream_t stream)
{
    const float* x        = (const float*)d_in[0];
    const float* codebook = (const float*)d_in[1];
    const float* Wq       = (const float*)d_in[2];
    const float* bq       = (const float*)d_in[3];
    const float* Wk       = (const float*)d_in[4];
    // d_in[5] = bk: per-row-constant shift in dots (top-k & softmax invariant)
    const float* Wv       = (const float*)d_in[6];
    const float* bv       = (const float*)d_in[7];
    float* out = (float*)d_out;

    // workspace (~61 MB)
    float* q2   = (float*)d_ws;                       // 4096x512
    float* Wqk  = q2   + (size_t)BATCH * DIM;         // 512x512
    float* bqk  = Wqk  + (size_t)DIM * DIM;           // 512 (pad 1024)
    float* y    = bqk  + 1024;                        // 4096x512
    float* trow = y    + (size_t)BATCH * DIM;         // 4096
    float* sigr = trow + BATCH;                       // 4096
    unsigned* counters = (unsigned*)(sigr + BATCH);   // 4096
    unsigned* flags    = counters + BATCH;            // 4096
    float* cbarsum     = (float*)(flags + BATCH);     // 512
    unsigned* candBuf  = (unsigned*)(cbarsum + 512);  // 4096x512 u32 (8 MB)
    u16* q2h = (u16*)(candBuf + (size_t)BATCH * CAND_CAP);   // 4 MB
    u16* cbh = q2h + (size_t)BATCH * DIM;                    // 32 MB

    dim3 blk(256);

    // zero counters+flags+cbarsum (contiguous: counters..cbarsum = 8704 u32)
    zero_ws<<<dim3(34), blk, 0, stream>>>(counters, BATCH * 2 + 512);

    // Wqk = Wq @ Wk^T ; bqk = bq @ Wk^T ; q2 = x @ Wqk + bqk
    gemm_kernel<true, true><<<dim3(DIM / 64, DIM / 128), blk, 0, stream>>>(
        Wq, Wk, nullptr, Wqk, DIM, DIM, DIM);
    bias_fold<<<dim3(2), blk, 0, stream>>>(bq, Wk, bqk);
    gemm_kernel<false, true><<<dim3(DIM / 64, BATCH / 128), blk, 0, stream>>>(
        x, Wqk, bqk, q2, BATCH, DIM, DIM);

    // analytic per-row candidate threshold
    cbar_accum<<<dim3(VOC / 512), blk, 0, stream>>>(codebook, cbarsum);
    rowstats<<<dim3(BATCH / 4), blk, 0, stream>>>(q2, cbarsum, trow, sigr);

    // pack MFMA operands (bf16 hi only)
    pack_rows<<<dim3(BATCH * 64 / 256), blk, 0, stream>>>(q2, q2h, BATCH, 12);
    pack_rows<<<dim3(VOC * 64 / 256), blk, 0, stream>>>(codebook, cbh, VOC, 15);

    // fused dots GEMM + candidate append (no dots materialization)
    mfma_dots<<<dim3(VOC / 128, BATCH / 128), blk, 0, stream>>>(
        q2h, cbh, trow, candBuf, counters);

    // exact selection + softmax + y = attn @ codebook
    select4<<<dim3(BATCH), blk, 0, stream>>>(
        candBuf, counters, trow, q2, codebook, y, flags);
    fallback_row<<<dim3(BATCH), blk, 0, stream>>>(
        flags, q2, codebook, trow, sigr, y);

    // out = y @ Wv + bv   (linearity: attn @ (cb@Wv+bv) = (attn@cb)@Wv + bv)
    gemm_kernel<false, false><<<dim3(DIM / 64, BATCH / 128), blk, 0, stream>>>(
        y, Wv, bv, out, BATCH, DIM, DIM);
}

// Round 6
// 991.781 us; speedup vs baseline: 1.0377x; 1.0377x over previous
//
#include <hip/hip_runtime.h>
#include <cstdint>

#define VOC   32768
#define DIM   512
#define TOPK  64
#define BATCH 4096

#define KSIG     2.45f
#define EPS_SEL  0.012f
#define CAND_CAP 512
#define RES_CAP  256
#define FCAP     1024

typedef unsigned short u16;
typedef __attribute__((ext_vector_type(8))) short bf16x8;
typedef __attribute__((ext_vector_type(4))) float f32x4;

// ---- bf16 helpers (RNE) ----------------------------------------------------
__device__ __forceinline__ u16 f2bf(float f) {
    unsigned u = __float_as_uint(f);
    unsigned r = (u + 0x7FFFu + ((u >> 16) & 1u)) >> 16;
    return (u16)r;
}
__device__ __forceinline__ float bf2f(u16 h) {
    return __uint_as_float(((unsigned)h) << 16);
}
__device__ __forceinline__ unsigned enc16(u16 h) {
    return (h & 0x8000u) ? (unsigned)((u16)~h) : (unsigned)(h | 0x8000u);
}
__device__ __forceinline__ float dec16(unsigned s16) {
    u16 h = (s16 & 0x8000u) ? (u16)(s16 ^ 0x8000u) : (u16)(~s16);
    return bf2f(h);
}

// ---- async global->LDS 16B -------------------------------------------------
__device__ __forceinline__ void async16(const void* g, void* l) {
    __builtin_amdgcn_global_load_lds(
        (const __attribute__((address_space(1))) void*)g,
        (__attribute__((address_space(3))) void*)l, 16, 0, 0);
}

// ---------------------------------------------------------------------------
// fp32 64x64-tile GEMM + optional per-k-tile fp64 flush. 256 thr, 4x4 micro.
//   BT=false: C = A(MxK) @ B(KxN) (+bias);  BT=true: C = A @ B^T (B NxK)
// ---------------------------------------------------------------------------
template <bool BT, bool F64ACC>
__global__ __launch_bounds__(256)
void gemm64(const float* __restrict__ A, const float* __restrict__ B,
            const float* __restrict__ bias, float* __restrict__ C,
            int M, int N, int K)
{
    const int KS = 16;
    __shared__ float As[KS][68];
    __shared__ float Bs[KS][64];

    const int tid = threadIdx.x;
    const int m0 = blockIdx.y * 64;
    const int n0 = blockIdx.x * 64;
    const int ty = tid >> 4;
    const int tx = tid & 15;

    float acc[4][4];
    double acc64[4][4];
#pragma unroll
    for (int i = 0; i < 4; i++)
#pragma unroll
        for (int j = 0; j < 4; j++) { acc[i][j] = 0.f; if (F64ACC) acc64[i][j] = 0.0; }

    for (int kt = 0; kt < K; kt += KS) {
        {
            int row = tid >> 2, kq = tid & 3;
            const float4 av = *(const float4*)(A + (size_t)(m0 + row) * K + kt + kq * 4);
            As[kq * 4 + 0][row] = av.x;
            As[kq * 4 + 1][row] = av.y;
            As[kq * 4 + 2][row] = av.z;
            As[kq * 4 + 3][row] = av.w;
        }
        if (!BT) {
            int krow = tid >> 4, nq = tid & 15;
            *(float4*)&Bs[krow][nq * 4] =
                *(const float4*)(B + (size_t)(kt + krow) * N + n0 + nq * 4);
        } else {
            int nrow = tid >> 2, kq = tid & 3;
            const float4 bv = *(const float4*)(B + (size_t)(n0 + nrow) * K + kt + kq * 4);
            Bs[kq * 4 + 0][nrow] = bv.x;
            Bs[kq * 4 + 1][nrow] = bv.y;
            Bs[kq * 4 + 2][nrow] = bv.z;
            Bs[kq * 4 + 3][nrow] = bv.w;
        }
        __syncthreads();

#pragma unroll
        for (int kk = 0; kk < KS; kk++) {
            float4 a = *(const float4*)&As[kk][ty * 4];
            float4 b = *(const float4*)&Bs[kk][tx * 4];
            float av[4] = {a.x, a.y, a.z, a.w};
            float bv[4] = {b.x, b.y, b.z, b.w};
#pragma unroll
            for (int i = 0; i < 4; i++)
#pragma unroll
                for (int j = 0; j < 4; j++)
                    acc[i][j] += av[i] * bv[j];
        }
        __syncthreads();
        if (F64ACC) {
#pragma unroll
            for (int i = 0; i < 4; i++)
#pragma unroll
                for (int j = 0; j < 4; j++) { acc64[i][j] += (double)acc[i][j]; acc[i][j] = 0.f; }
        }
    }

    float4 bb = make_float4(0.f, 0.f, 0.f, 0.f);
    if (bias) bb = *(const float4*)(bias + n0 + tx * 4);
#pragma unroll
    for (int i = 0; i < 4; i++) {
        float4 o;
        o.x = (F64ACC ? (float)acc64[i][0] : acc[i][0]) + bb.x;
        o.y = (F64ACC ? (float)acc64[i][1] : acc[i][1]) + bb.y;
        o.z = (F64ACC ? (float)acc64[i][2] : acc[i][2]) + bb.z;
        o.w = (F64ACC ? (float)acc64[i][3] : acc[i][3]) + bb.w;
        *(float4*)(C + (size_t)(m0 + ty * 4 + i) * N + n0 + tx * 4) = o;
    }
}

// ---------------------------------------------------------------------------
__global__ void bias_fold(const float* __restrict__ bq, const float* __restrict__ Wk,
                          float* __restrict__ bqk)
{
    int j = blockIdx.x * 256 + threadIdx.x;
    if (j >= DIM) return;
    double s = 0.0;
    const float* wr = Wk + (size_t)j * DIM;
    for (int d = 0; d < DIM; d++) s += (double)bq[d] * (double)wr[d];
    bqk[j] = (float)s;
}

__global__ void zero_ws(unsigned* __restrict__ p, int n)
{
    int i = blockIdx.x * 256 + threadIdx.x;
    if (i < n) p[i] = 0u;
}

// ---------------------------------------------------------------------------
// Column sums of codebook (for mu_row).
// ---------------------------------------------------------------------------
__global__ __launch_bounds__(256)
void cbar_accum(const float* __restrict__ cb, float* __restrict__ cbarsum)
{
    const int tid = threadIdx.x;
    const int r0 = blockIdx.x * 512;
    float s0 = 0.f, s1 = 0.f;
    for (int r = 0; r < 512; r++) {
        const float* rp = cb + (size_t)(r0 + r) * DIM;
        s0 += rp[tid];
        s1 += rp[tid + 256];
    }
    atomicAdd(&cbarsum[tid], s0);
    atomicAdd(&cbarsum[tid + 256], s1);
}

// ---------------------------------------------------------------------------
// Per-row analytic threshold: t = mu + KSIG*sigma, sigma = ||q2_row||/sqrt(1536).
// ---------------------------------------------------------------------------
__global__ __launch_bounds__(256)
void rowstats(const float* __restrict__ q2, const float* __restrict__ cbarsum,
              float* __restrict__ trow, float* __restrict__ sigrow)
{
    const int tid = threadIdx.x, lane = tid & 63, wave = tid >> 6;
    const int row = blockIdx.x * 4 + wave;
    const float* qp = q2 + (size_t)row * DIM + lane * 8;
    float4 a0 = *(const float4*)qp, a1 = *(const float4*)(qp + 4);
    const float* cp = cbarsum + lane * 8;
    float4 c0 = *(const float4*)cp, c1 = *(const float4*)(cp + 4);
    float mu = a0.x*c0.x + a0.y*c0.y + a0.z*c0.z + a0.w*c0.w
             + a1.x*c1.x + a1.y*c1.y + a1.z*c1.z + a1.w*c1.w;
    float nr = a0.x*a0.x + a0.y*a0.y + a0.z*a0.z + a0.w*a0.w
             + a1.x*a1.x + a1.y*a1.y + a1.z*a1.z + a1.w*a1.w;
#pragma unroll
    for (int off = 32; off > 0; off >>= 1) {
        mu += __shfl_down(mu, off);
        nr += __shfl_down(nr, off);
    }
    if (lane == 0) {
        mu *= (1.f / VOC);
        float sig = sqrtf(nr * (1.f / 1536.f));
        trow[row] = mu + KSIG * sig;
        sigrow[row] = sig;
    }
}

// ---------------------------------------------------------------------------
// Pack fp32 [R x 512] -> MFMA operand layout pk[ks][ch][R][8] bf16 (+opt lo).
// ---------------------------------------------------------------------------
__global__ __launch_bounds__(256)
void pack_rows(const float* __restrict__ src, u16* __restrict__ hi,
               u16* __restrict__ lo, int R, int log2R)
{
    int idx = blockIdx.x * 256 + threadIdx.x;
    int c8  = idx >> log2R;
    int row = idx & (R - 1);
    const float* sp = src + (size_t)row * DIM + c8 * 8;
    float xv[8];
    *(float4*)&xv[0] = *(const float4*)sp;
    *(float4*)&xv[4] = *(const float4*)(sp + 4);
    int ks = c8 >> 2, ch = c8 & 3;
    size_t ob = ((size_t)(ks * 4 + ch) * R + row) * 8;
    u16 h[8], l[8];
#pragma unroll
    for (int j = 0; j < 8; j++) {
        h[j] = f2bf(xv[j]);
        l[j] = f2bf(xv[j] - bf2f(h[j]));
    }
    *(uint4*)(hi + ob) = *(const uint4*)h;
    if (lo) *(uint4*)(lo + ob) = *(const uint4*)l;
}

// ---------------------------------------------------------------------------
// Pack Wv (B-operand: B[k][n]) -> pk[ks][ch][512(n)][8(k)] hi+lo
// ---------------------------------------------------------------------------
__global__ __launch_bounds__(256)
void pack_bT(const float* __restrict__ W, u16* __restrict__ hi, u16* __restrict__ lo)
{
    int idx = blockIdx.x * 256 + threadIdx.x;
    int n  = idx & (DIM - 1);
    int c8 = idx >> 9;
    int ks = c8 >> 2, ch = c8 & 3;
    size_t ob = ((size_t)(ks * 4 + ch) * DIM + n) * 8;
    u16 h[8], l[8];
#pragma unroll
    for (int j = 0; j < 8; j++) {
        float x = W[(size_t)(c8 * 8 + j) * DIM + n];
        h[j] = f2bf(x);
        l[j] = f2bf(x - bf2f(h[j]));
    }
    *(uint4*)(hi + ob) = *(const uint4*)h;
    *(uint4*)(lo + ob) = *(const uint4*)l;
}

// ---------------------------------------------------------------------------
// v = codebook @ Wv + bv  (bf16 hi/lo 3-pass MFMA, fp32 out). Round-3 proven.
// ---------------------------------------------------------------------------
__global__ __launch_bounds__(256, 2)
void mfma_v(const u16* __restrict__ Ah, const u16* __restrict__ Al,
            const u16* __restrict__ Bh, const u16* __restrict__ Bl,
            const float* __restrict__ bias, float* __restrict__ Cout)
{
    __shared__ u16 lds[4 * 4096];

    const int tid  = threadIdx.x;
    const int lane = tid & 63;
    const int wave = tid >> 6;
    const int wm = wave >> 1, wn = wave & 1;
    const int m0 = blockIdx.y * 128, n0 = blockIdx.x * 128;
    const int lr = lane & 15;
    const int q  = lane >> 4;

    f32x4 acc[4][4] = {};
    const u16* garr[4] = {Ah, Bh, Al, Bl};

    for (int ks = 0; ks < 16; ks++) {
        const int a = wave;
        const u16* src = garr[a];
        const bool isA = (a == 0 || a == 2);
        const int rb = isA ? m0 : n0;
        const size_t R = isA ? (size_t)VOC : (size_t)DIM;
#pragma unroll
        for (int i = 0; i < 8; i++) {
            const u16* gp = src + ((size_t)(ks * 4 + (i >> 1)) * R + rb + (i & 1) * 64 + lane) * 8;
            async16(gp, &lds[a * 4096 + i * 512 + lane * 8]);
        }
        __syncthreads();

        bf16x8 ah[4], al[4];
#pragma unroll
        for (int mt = 0; mt < 4; mt++) {
            int row = wm * 64 + mt * 16 + lr;
            ah[mt] = *(const bf16x8*)&lds[0 * 4096 + q * 1024 + row * 8];
            al[mt] = *(const bf16x8*)&lds[2 * 4096 + q * 1024 + row * 8];
        }
#pragma unroll
        for (int nt = 0; nt < 4; nt++) {
            int col = wn * 64 + nt * 16 + lr;
            bf16x8 bh = *(const bf16x8*)&lds[1 * 4096 + q * 1024 + col * 8];
            bf16x8 bl = *(const bf16x8*)&lds[3 * 4096 + q * 1024 + col * 8];
#pragma unroll
            for (int mt = 0; mt < 4; mt++) {
                acc[mt][nt] = __builtin_amdgcn_mfma_f32_16x16x32_bf16(ah[mt], bh, acc[mt][nt], 0, 0, 0);
                acc[mt][nt] = __builtin_amdgcn_mfma_f32_16x16x32_bf16(ah[mt], bl, acc[mt][nt], 0, 0, 0);
                acc[mt][nt] = __builtin_amdgcn_mfma_f32_16x16x32_bf16(al[mt], bh, acc[mt][nt], 0, 0, 0);
            }
        }
        __syncthreads();
    }

#pragma unroll
    for (int mt = 0; mt < 4; mt++)
#pragma unroll
        for (int nt = 0; nt < 4; nt++) {
            int col = n0 + wn * 64 + nt * 16 + lr;
            float bb = bias[col];
#pragma unroll
            for (int r = 0; r < 4; r++) {
                int rowg = m0 + wm * 64 + mt * 16 + q * 4 + r;
                Cout[(size_t)rowg * DIM + col] = acc[mt][nt][r] + bb;
            }
        }
}

// ---------------------------------------------------------------------------
// Fused dots GEMM v2: 3-stage LDS pipeline (raw s_barrier + vmcnt(4): next
// stage's global_load_lds stay in flight across the barrier) + XCD swizzle
// (each XCD owns a 32-n-tile cbh slice = 4MB = its L2). Epilogue appends
// candidates (val >= trow[row]) as (sortkey16<<16 | idx); dots never stored.
// ---------------------------------------------------------------------------
__global__ __launch_bounds__(256, 2)
void mfma_dots(const u16* __restrict__ Ah, const u16* __restrict__ Bh,
               const float* __restrict__ trow, unsigned* __restrict__ candBuf,
               unsigned* __restrict__ counters)
{
    __shared__ u16 lds[3 * 8192];      // 3 stages x (A 4096 + B 4096) u16

    const int tid  = threadIdx.x;
    const int lane = tid & 63;
    const int wave = tid >> 6;
    const int wm = wave >> 1, wn = wave & 1;
    const int lr = lane & 15;
    const int q  = lane >> 4;

    // XCD swizzle: consecutive blocks round-robin XCDs; give XCD k the
    // n-tile slice [k*32, k*32+32) so its L2 holds that 4MB cbh slice.
    const int L   = blockIdx.x;
    const int xcd = L & 7;
    const int g   = L >> 3;
    const int m0  = (g >> 5) * 128;
    const int n0  = ((xcd << 5) | (g & 31)) * 128;

    const int a  = wave >> 1;                  // 0: stage A (q2h), 1: stage B (cbh)
    const u16* src = a ? Bh : Ah;
    const int rb   = a ? n0 : m0;
    const size_t R = a ? (size_t)VOC : (size_t)BATCH;
    const int i0   = (wave & 1) * 4;

    f32x4 acc[4][4] = {};

#define ISSUE(ks, b)                                                          \
    {                                                                         \
        _Pragma("unroll")                                                     \
        for (int s_ = 0; s_ < 4; s_++) {                                      \
            int i_ = i0 + s_;                                                 \
            const u16* gp_ = src + ((size_t)((ks) * 4 + (i_ >> 1)) * R + rb   \
                                    + (i_ & 1) * 64 + lane) * 8;              \
            async16(gp_, &lds[(b) * 8192 + a * 4096 + i_ * 512 + lane * 8]);  \
        }                                                                     \
    }

    ISSUE(0, 0)
    ISSUE(1, 1)

    for (int s = 0; s < 16; s++) {
        // wait for stage s only (stage s+1's 4 loads keep flying); raw barrier
        if (s == 15) __builtin_amdgcn_s_waitcnt(0x0F70);   // vmcnt(0)
        else         __builtin_amdgcn_s_waitcnt(0x0F74);   // vmcnt(4)
        __builtin_amdgcn_s_barrier();
        if (s < 14) {
            int b2 = (s + 2) % 3;
            ISSUE(s + 2, b2)
        }
        const u16* base = &lds[(s % 3) * 8192];

        bf16x8 ah[4];
#pragma unroll
        for (int mt = 0; mt < 4; mt++)
            ah[mt] = *(const bf16x8*)&base[q * 1024 + (wm * 64 + mt * 16 + lr) * 8];
#pragma unroll
        for (int nt = 0; nt < 4; nt++) {
            bf16x8 bh = *(const bf16x8*)&base[4096 + q * 1024 + (wn * 64 + nt * 16 + lr) * 8];
#pragma unroll
            for (int mt = 0; mt < 4; mt++)
                acc[mt][nt] = __builtin_amdgcn_mfma_f32_16x16x32_bf16(ah[mt], bh, acc[mt][nt], 0, 0, 0);
        }
    }
#undef ISSUE

    // epilogue: threshold-append candidates
#pragma unroll
    for (int mt = 0; mt < 4; mt++) {
#pragma unroll
        for (int r = 0; r < 4; r++) {
            int rowg = m0 + wm * 64 + mt * 16 + q * 4 + r;
            float tr = trow[rowg];
#pragma unroll
            for (int nt = 0; nt < 4; nt++) {
                float val = acc[mt][nt][r];
                if (val >= tr) {
                    unsigned slot = atomicAdd(&counters[rowg], 1u);
                    if (slot < CAND_CAP) {
                        unsigned s16 = enc16(f2bf(val));
                        candBuf[(size_t)rowg * CAND_CAP + slot] =
                            (s16 << 16) | (unsigned)(n0 + wn * 64 + nt * 16 + lr);
                    }
                }
            }
        }
    }
}

// ---------------------------------------------------------------------------
// Select v5: sort candidates by approx -> verify t <= a64 - 2*EPS (proof of
// top-64 coverage) -> fp64 rescue of band -> exact sort -> thresh (ties) ->
// softmax -> out_row = sum w_i * v[idx_i].  Anomalies -> flags (fallback).
// ---------------------------------------------------------------------------
__global__ __launch_bounds__(256)
void select5(const unsigned* __restrict__ candBuf, const unsigned* __restrict__ counters,
             const float* __restrict__ trow, const float* __restrict__ q2,
             const float* __restrict__ codebook, const float* __restrict__ v,
             float* __restrict__ out, unsigned* __restrict__ flags)
{
    __shared__ unsigned recs[CAND_CAP];
    __shared__ unsigned long long keys[RES_CAP];
    __shared__ float q2s[DIM];
    __shared__ float wArr[RES_CAP];
    __shared__ float redf[256];
    __shared__ unsigned redu[256];
    __shared__ unsigned s_R;

    const int tid  = threadIdx.x;
    const int lane = tid & 63;
    const int wave = tid >> 6;
    const int row  = blockIdx.x;

    const unsigned cnt = counters[row];
    if (cnt < TOPK || cnt > CAND_CAP) {
        if (tid == 0) flags[row] = 1u;
        return;
    }
    for (int i = tid; i < DIM; i += 256) q2s[i] = q2[(size_t)row * DIM + i];
    for (int i = tid; i < CAND_CAP; i += 256)
        recs[i] = (i < (int)cnt) ? candBuf[(size_t)row * CAND_CAP + i] : 0u;
    if (tid == 0) s_R = 0;
    __syncthreads();

    // bitonic sort 512 u32 DESCENDING (sortkey high 16 bits; pads=0 last)
    for (int k = 2; k <= CAND_CAP; k <<= 1) {
        for (int j = k >> 1; j > 0; j >>= 1) {
#pragma unroll
            for (int e = 0; e < 2; e++) {
                int i = tid + e * 256;
                int ixj = i ^ j;
                if (ixj > i) {
                    unsigned a = recs[i], b = recs[ixj];
                    if (((i & k) == 0) ? (a < b) : (a > b)) { recs[i] = b; recs[ixj] = a; }
                }
            }
            __syncthreads();
        }
    }

    const float a64  = dec16(recs[TOPK - 1] >> 16);
    const float band = a64 - 2.f * EPS_SEL;
    if (trow[row] > band) {
        if (tid == 0) flags[row] = 1u;
        return;
    }

#pragma unroll
    for (int e = 0; e < 2; e++) {
        int i = tid + e * 256;
        if (i < (int)cnt && dec16(recs[i] >> 16) >= band) atomicAdd(&s_R, 1u);
    }
    __syncthreads();
    const int R = (int)s_R;
    if (R > RES_CAP) {
        if (tid == 0) flags[row] = 1u;
        return;
    }

    // fp64 rescue: wave per candidate, coalesced codebook reads
    for (int c = wave; c < R; c += 4) {
        unsigned idx = recs[c] & 0xFFFFu;
        const float* cb = codebook + (size_t)idx * DIM + lane * 8;
        float4 c0 = *(const float4*)cb, c1 = *(const float4*)(cb + 4);
        const float* qp = &q2s[lane * 8];
        float4 a0 = *(const float4*)qp, a1 = *(const float4*)(qp + 4);
        double s = (double)a0.x * c0.x + (double)a0.y * c0.y
                 + (double)a0.z * c0.z + (double)a0.w * c0.w
                 + (double)a1.x * c1.x + (double)a1.y * c1.y
                 + (double)a1.z * c1.z + (double)a1.w * c1.w;
#pragma unroll
        for (int off = 32; off > 0; off >>= 1) s += __shfl_down(s, off);
        if (lane == 0) {
            float val = (float)s;
            unsigned b = __float_as_uint(val);
            unsigned sk = (b & 0x80000000u) ? ~b : (b | 0x80000000u);
            keys[c] = ((unsigned long long)(~sk) << 32) | idx;
        }
    }
    if (tid >= R && tid < RES_CAP) keys[tid] = ~0ULL;
    __syncthreads();

    // bitonic sort 256 u64 ascending (= descending by exact value)
    for (int k = 2; k <= RES_CAP; k <<= 1) {
        for (int j = k >> 1; j > 0; j >>= 1) {
            int ixj = tid ^ j;
            if (ixj > tid) {
                unsigned long long a = keys[tid], b2 = keys[ixj];
                if (((tid & k) == 0) ? (a > b2) : (a < b2)) { keys[tid] = b2; keys[ixj] = a; }
            }
            __syncthreads();
        }
    }

    const unsigned threshInv = (unsigned)(keys[TOPK - 1] >> 32);
    unsigned sk0 = ~(unsigned)(keys[0] >> 32);
    const float vmax = __uint_as_float((sk0 & 0x80000000u) ? (sk0 & 0x7FFFFFFFu) : ~sk0);

    unsigned hi = (unsigned)(keys[tid] >> 32);
    bool sel = (hi <= threshInv);
    unsigned sk = ~hi;
    float val = __uint_as_float((sk & 0x80000000u) ? (sk & 0x7FFFFFFFu) : ~sk);
    float w = sel ? expf(val - vmax) : 0.f;
    wArr[tid] = w;
    redf[tid] = w;
    redu[tid] = sel ? 1u : 0u;
    __syncthreads();
    for (int s = 128; s > 0; s >>= 1) {
        if (tid < s) { redf[tid] += redf[tid + s]; redu[tid] += redu[tid + s]; }
        __syncthreads();
    }
    const float invZ = 1.0f / redf[0];
    const int selCount = (int)redu[0];

    for (int d = tid; d < DIM; d += 256) {
        float acc = 0.f;
        for (int i = 0; i < selCount; i++) {
            unsigned idx = (unsigned)(keys[i] & 0xFFFFFFFFu);
            acc += wArr[i] * v[(size_t)idx * DIM + d];
        }
        out[(size_t)row * DIM + d] = acc * invZ;
    }
}

// ---------------------------------------------------------------------------
// Exact fallback for flagged rows (expected: none). fp64 scan over all VOC.
// ---------------------------------------------------------------------------
__global__ __launch_bounds__(256)
void fallback_row(const unsigned* __restrict__ flags, const float* __restrict__ q2,
                  const float* __restrict__ codebook, const float* __restrict__ v,
                  const float* __restrict__ trow, const float* __restrict__ sigrow,
                  float* __restrict__ out)
{
    const int row = blockIdx.x;
    if (!flags[row]) return;

    __shared__ float q2s[DIM];
    __shared__ unsigned long long keys[FCAP];
    __shared__ float wArr[FCAP];
    __shared__ float redf[256];
    __shared__ unsigned redu[256];
    __shared__ unsigned s_cnt;

    const int tid = threadIdx.x;
    for (int i = tid; i < DIM; i += 256) q2s[i] = q2[(size_t)row * DIM + i];
    const float sig = sigrow[row];
    float tf = trow[row] - 0.35f * sig;
    unsigned cnt = 0;

    for (int it = 0; it < 16; it++) {
        if (tid == 0) s_cnt = 0;
        __syncthreads();
        for (int i = tid; i < VOC; i += 256) {
            const float* cb = codebook + (size_t)i * DIM;
            double s = 0.0;
            for (int d = 0; d < DIM; d += 4) {
                float4 c4 = *(const float4*)(cb + d);
                s += (double)q2s[d + 0] * (double)c4.x + (double)q2s[d + 1] * (double)c4.y
                   + (double)q2s[d + 2] * (double)c4.z + (double)q2s[d + 3] * (double)c4.w;
            }
            float vv = (float)s;
            if (vv >= tf) {
                unsigned p = atomicAdd(&s_cnt, 1u);
                if (p < FCAP) {
                    unsigned b = __float_as_uint(vv);
                    unsigned sk = (b & 0x80000000u) ? ~b : (b | 0x80000000u);
                    keys[p] = ((unsigned long long)(~sk) << 32) | (unsigned)i;
                }
            }
        }
        __syncthreads();
        cnt = s_cnt;
        if (cnt > FCAP) { tf += 0.15f * sig; continue; }
        if (cnt < TOPK) { tf -= 0.35f * sig; continue; }
        break;
    }
    if (cnt > FCAP) cnt = FCAP;
    for (int i = tid; i < FCAP; i += 256)
        if (i >= (int)cnt) keys[i] = ~0ULL;
    __syncthreads();

    for (int k = 2; k <= FCAP; k <<= 1) {
        for (int j = k >> 1; j > 0; j >>= 1) {
#pragma unroll
            for (int e = 0; e < 4; e++) {
                int i = tid + e * 256;
                int ixj = i ^ j;
                if (ixj > i) {
                    unsigned long long a = keys[i], b = keys[ixj];
                    if (((i & k) == 0) ? (a > b) : (a < b)) { keys[i] = b; keys[ixj] = a; }
                }
            }
            __syncthreads();
        }
    }

    const unsigned threshInv = (unsigned)(keys[TOPK - 1] >> 32);
    unsigned sk0 = ~(unsigned)(keys[0] >> 32);
    const float vmax = __uint_as_float((sk0 & 0x80000000u) ? (sk0 & 0x7FFFFFFFu) : ~sk0);

    float lsum = 0.f; unsigned lcnt = 0;
    for (int i = tid; i < FCAP; i += 256) {
        unsigned hi = (unsigned)(keys[i] >> 32);
        bool sel = (hi <= threshInv);
        unsigned sk = ~hi;
        float vv = __uint_as_float((sk & 0x80000000u) ? (sk & 0x7FFFFFFFu) : ~sk);
        float w = sel ? expf(vv - vmax) : 0.f;
        wArr[i] = w;
        lsum += w; lcnt += sel ? 1u : 0u;
    }
    redf[tid] = lsum; redu[tid] = lcnt;
    __syncthreads();
    for (int s = 128; s > 0; s >>= 1) {
        if (tid < s) { redf[tid] += redf[tid + s]; redu[tid] += redu[tid + s]; }
        __syncthreads();
    }
    const float invZ = 1.f / redf[0];
    const int selCount = (int)redu[0];

    for (int d = tid; d < DIM; d += 256) {
        float acc = 0.f;
        for (int i = 0; i < selCount; i++) {
            unsigned idx = (unsigned)(keys[i] & 0xFFFFFFFFu);
            acc += wArr[i] * v[(size_t)idx * DIM + d];
        }
        out[(size_t)row * DIM + d] = acc * invZ;
    }
}

// ---------------------------------------------------------------------------
extern "C" void kernel_launch(void* const* d_in, const int* in_sizes, int n_in,
                              void* d_out, int out_size, void* d_ws, size_t ws_size,
                              hipStream_t stream)
{
    const float* x        = (const float*)d_in[0];
    const float* codebook = (const float*)d_in[1];
    const float* Wq       = (const float*)d_in[2];
    const float* bq       = (const float*)d_in[3];
    const float* Wk       = (const float*)d_in[4];
    // d_in[5] = bk: per-row-constant shift in dots (top-k & softmax invariant)
    const float* Wv       = (const float*)d_in[6];
    const float* bv       = (const float*)d_in[7];
    float* out = (float*)d_out;

    // workspace (~150 MB)
    float* q2   = (float*)d_ws;                       // 4096x512   (8 MB)
    float* Wqk  = q2   + (size_t)BATCH * DIM;         // 512x512    (1 MB)
    float* bqk  = Wqk  + (size_t)DIM * DIM;           // 512 (pad 1024)
    float* v    = bqk  + 1024;                        // 32768x512  (64 MB)
    float* trow = v    + (size_t)VOC * DIM;           // 4096
    float* sigr = trow + BATCH;                       // 4096
    unsigned* counters = (unsigned*)(sigr + BATCH);   // 4096
    unsigned* flags    = counters + BATCH;            // 4096
    float* cbarsum     = (float*)(flags + BATCH);     // 512
    unsigned* candBuf  = (unsigned*)(cbarsum + 512);  // 4096x512 (8 MB)
    u16* q2h = (u16*)(candBuf + (size_t)BATCH * CAND_CAP);   // 4 MB
    u16* cbh = q2h + (size_t)BATCH * DIM;                    // 32 MB
    u16* cbl = cbh + (size_t)VOC * DIM;                      // 32 MB
    u16* wvh = cbl + (size_t)VOC * DIM;                      // 0.5 MB
    u16* wvl = wvh + (size_t)DIM * DIM;                      // 0.5 MB

    dim3 blk(256);

    // zero counters+flags+cbarsum (contiguous 8704 words)
    zero_ws<<<dim3(34), blk, 0, stream>>>(counters, BATCH * 2 + 512);

    // Wqk = Wq @ Wk^T ; bqk = bq @ Wk^T ; q2 = x @ Wqk + bqk (selection-critical)
    gemm64<true, true><<<dim3(DIM / 64, DIM / 64), blk, 0, stream>>>(
        Wq, Wk, nullptr, Wqk, DIM, DIM, DIM);
    bias_fold<<<dim3(2), blk, 0, stream>>>(bq, Wk, bqk);
    gemm64<false, true><<<dim3(DIM / 64, BATCH / 64), blk, 0, stream>>>(
        x, Wqk, bqk, q2, BATCH, DIM, DIM);

    // analytic per-row candidate threshold
    cbar_accum<<<dim3(VOC / 512), blk, 0, stream>>>(codebook, cbarsum);
    rowstats<<<dim3(BATCH / 4), blk, 0, stream>>>(q2, cbarsum, trow, sigr);

    // pack MFMA operands
    pack_rows<<<dim3(BATCH * 64 / 256), blk, 0, stream>>>(q2, q2h, nullptr, BATCH, 12);
    pack_rows<<<dim3(VOC * 64 / 256), blk, 0, stream>>>(codebook, cbh, cbl, VOC, 15);
    pack_bT<<<dim3(DIM * 64 / 256), blk, 0, stream>>>(Wv, wvh, wvl);

    // fused dots GEMM (pipelined, XCD-swizzled) + candidate append
    mfma_dots<<<dim3(8192), blk, 0, stream>>>(q2h, cbh, trow, candBuf, counters);

    // v = codebook @ Wv + bv (hi/lo 3-pass MFMA)
    mfma_v<<<dim3(DIM / 128, VOC / 128), blk, 0, stream>>>(cbh, cbl, wvh, wvl, bv, v);

    // exact selection + softmax + out = attn @ v
    select5<<<dim3(BATCH), blk, 0, stream>>>(
        candBuf, counters, trow, q2, codebook, v, out, flags);
    fallback_row<<<dim3(BATCH), blk, 0, stream>>>(
        flags, q2, codebook, v, trow, sigr, out);
}

// Round 7
// 784.256 us; speedup vs baseline: 1.3123x; 1.2646x over previous
//
#include <hip/hip_runtime.h>
#include <cstdint>

#define VOC   32768
#define DIM   512
#define TOPK  64
#define BATCH 4096

#define KSIG     2.45f
#define EPS_SEL  0.012f
#define CAND_CAP 512
#define RES_CAP  256
#define FCAP     1024

typedef unsigned short u16;
typedef __attribute__((ext_vector_type(8))) short bf16x8;
typedef __attribute__((ext_vector_type(4))) float f32x4;

// ---- bf16 helpers (RNE) ----------------------------------------------------
__device__ __forceinline__ u16 f2bf(float f) {
    unsigned u = __float_as_uint(f);
    unsigned r = (u + 0x7FFFu + ((u >> 16) & 1u)) >> 16;
    return (u16)r;
}
__device__ __forceinline__ float bf2f(u16 h) {
    return __uint_as_float(((unsigned)h) << 16);
}
__device__ __forceinline__ unsigned enc16(u16 h) {
    return (h & 0x8000u) ? (unsigned)((u16)~h) : (unsigned)(h | 0x8000u);
}
__device__ __forceinline__ float dec16(unsigned s16) {
    u16 h = (s16 & 0x8000u) ? (u16)(s16 ^ 0x8000u) : (u16)(~s16);
    return bf2f(h);
}

// ---- async global->LDS 16B -------------------------------------------------
__device__ __forceinline__ void async16(const void* g, void* l) {
    __builtin_amdgcn_global_load_lds(
        (const __attribute__((address_space(1))) void*)g,
        (__attribute__((address_space(3))) void*)l, 16, 0, 0);
}

// ---------------------------------------------------------------------------
// fp32 64x64-tile GEMM + optional per-k-tile fp64 flush. 256 thr, 4x4 micro.
//   BT=false: C = A(MxK) @ B(KxN) (+bias);  BT=true: C = A @ B^T (B NxK)
// ---------------------------------------------------------------------------
template <bool BT, bool F64ACC>
__global__ __launch_bounds__(256)
void gemm64(const float* __restrict__ A, const float* __restrict__ B,
            const float* __restrict__ bias, float* __restrict__ C,
            int M, int N, int K)
{
    const int KS = 16;
    __shared__ float As[KS][68];
    __shared__ float Bs[KS][64];

    const int tid = threadIdx.x;
    const int m0 = blockIdx.y * 64;
    const int n0 = blockIdx.x * 64;
    const int ty = tid >> 4;
    const int tx = tid & 15;

    float acc[4][4];
    double acc64[4][4];
#pragma unroll
    for (int i = 0; i < 4; i++)
#pragma unroll
        for (int j = 0; j < 4; j++) { acc[i][j] = 0.f; if (F64ACC) acc64[i][j] = 0.0; }

    for (int kt = 0; kt < K; kt += KS) {
        {
            int row = tid >> 2, kq = tid & 3;
            const float4 av = *(const float4*)(A + (size_t)(m0 + row) * K + kt + kq * 4);
            As[kq * 4 + 0][row] = av.x;
            As[kq * 4 + 1][row] = av.y;
            As[kq * 4 + 2][row] = av.z;
            As[kq * 4 + 3][row] = av.w;
        }
        if (!BT) {
            int krow = tid >> 4, nq = tid & 15;
            *(float4*)&Bs[krow][nq * 4] =
                *(const float4*)(B + (size_t)(kt + krow) * N + n0 + nq * 4);
        } else {
            int nrow = tid >> 2, kq = tid & 3;
            const float4 bv = *(const float4*)(B + (size_t)(n0 + nrow) * K + kt + kq * 4);
            Bs[kq * 4 + 0][nrow] = bv.x;
            Bs[kq * 4 + 1][nrow] = bv.y;
            Bs[kq * 4 + 2][nrow] = bv.z;
            Bs[kq * 4 + 3][nrow] = bv.w;
        }
        __syncthreads();

#pragma unroll
        for (int kk = 0; kk < KS; kk++) {
            float4 a = *(const float4*)&As[kk][ty * 4];
            float4 b = *(const float4*)&Bs[kk][tx * 4];
            float av[4] = {a.x, a.y, a.z, a.w};
            float bv[4] = {b.x, b.y, b.z, b.w};
#pragma unroll
            for (int i = 0; i < 4; i++)
#pragma unroll
                for (int j = 0; j < 4; j++)
                    acc[i][j] += av[i] * bv[j];
        }
        __syncthreads();
        if (F64ACC) {
#pragma unroll
            for (int i = 0; i < 4; i++)
#pragma unroll
                for (int j = 0; j < 4; j++) { acc64[i][j] += (double)acc[i][j]; acc[i][j] = 0.f; }
        }
    }

    float4 bb = make_float4(0.f, 0.f, 0.f, 0.f);
    if (bias) bb = *(const float4*)(bias + n0 + tx * 4);
#pragma unroll
    for (int i = 0; i < 4; i++) {
        float4 o;
        o.x = (F64ACC ? (float)acc64[i][0] : acc[i][0]) + bb.x;
        o.y = (F64ACC ? (float)acc64[i][1] : acc[i][1]) + bb.y;
        o.z = (F64ACC ? (float)acc64[i][2] : acc[i][2]) + bb.z;
        o.w = (F64ACC ? (float)acc64[i][3] : acc[i][3]) + bb.w;
        *(float4*)(C + (size_t)(m0 + ty * 4 + i) * N + n0 + tx * 4) = o;
    }
}

// ---------------------------------------------------------------------------
__global__ void bias_fold(const float* __restrict__ bq, const float* __restrict__ Wk,
                          float* __restrict__ bqk)
{
    int j = blockIdx.x * 256 + threadIdx.x;
    if (j >= DIM) return;
    double s = 0.0;
    const float* wr = Wk + (size_t)j * DIM;
    for (int d = 0; d < DIM; d++) s += (double)bq[d] * (double)wr[d];
    bqk[j] = (float)s;
}

__global__ void zero_ws(unsigned* __restrict__ p, int n)
{
    int i = blockIdx.x * 256 + threadIdx.x;
    if (i < n) p[i] = 0u;
}

// ---------------------------------------------------------------------------
// Column sums of codebook (for mu_row).
// ---------------------------------------------------------------------------
__global__ __launch_bounds__(256)
void cbar_accum(const float* __restrict__ cb, float* __restrict__ cbarsum)
{
    const int tid = threadIdx.x;
    const int r0 = blockIdx.x * 512;
    float s0 = 0.f, s1 = 0.f;
    for (int r = 0; r < 512; r++) {
        const float* rp = cb + (size_t)(r0 + r) * DIM;
        s0 += rp[tid];
        s1 += rp[tid + 256];
    }
    atomicAdd(&cbarsum[tid], s0);
    atomicAdd(&cbarsum[tid + 256], s1);
}

// ---------------------------------------------------------------------------
// Per-row analytic threshold: t = mu + KSIG*sigma, sigma = ||q2_row||/sqrt(1536).
// ---------------------------------------------------------------------------
__global__ __launch_bounds__(256)
void rowstats(const float* __restrict__ q2, const float* __restrict__ cbarsum,
              float* __restrict__ trow, float* __restrict__ sigrow)
{
    const int tid = threadIdx.x, lane = tid & 63, wave = tid >> 6;
    const int row = blockIdx.x * 4 + wave;
    const float* qp = q2 + (size_t)row * DIM + lane * 8;
    float4 a0 = *(const float4*)qp, a1 = *(const float4*)(qp + 4);
    const float* cp = cbarsum + lane * 8;
    float4 c0 = *(const float4*)cp, c1 = *(const float4*)(cp + 4);
    float mu = a0.x*c0.x + a0.y*c0.y + a0.z*c0.z + a0.w*c0.w
             + a1.x*c1.x + a1.y*c1.y + a1.z*c1.z + a1.w*c1.w;
    float nr = a0.x*a0.x + a0.y*a0.y + a0.z*a0.z + a0.w*a0.w
             + a1.x*a1.x + a1.y*a1.y + a1.z*a1.z + a1.w*a1.w;
#pragma unroll
    for (int off = 32; off > 0; off >>= 1) {
        mu += __shfl_down(mu, off);
        nr += __shfl_down(nr, off);
    }
    if (lane == 0) {
        mu *= (1.f / VOC);
        float sig = sqrtf(nr * (1.f / 1536.f));
        trow[row] = mu + KSIG * sig;
        sigrow[row] = sig;
    }
}

// ---------------------------------------------------------------------------
// Pack fp32 [R x 512] -> MFMA operand layout pk[ks][ch][R][8] bf16 (+opt lo).
// ---------------------------------------------------------------------------
__global__ __launch_bounds__(256)
void pack_rows(const float* __restrict__ src, u16* __restrict__ hi,
               u16* __restrict__ lo, int R, int log2R)
{
    int idx = blockIdx.x * 256 + threadIdx.x;
    int c8  = idx >> log2R;
    int row = idx & (R - 1);
    const float* sp = src + (size_t)row * DIM + c8 * 8;
    float xv[8];
    *(float4*)&xv[0] = *(const float4*)sp;
    *(float4*)&xv[4] = *(const float4*)(sp + 4);
    int ks = c8 >> 2, ch = c8 & 3;
    size_t ob = ((size_t)(ks * 4 + ch) * R + row) * 8;
    u16 h[8], l[8];
#pragma unroll
    for (int j = 0; j < 8; j++) {
        h[j] = f2bf(xv[j]);
        l[j] = f2bf(xv[j] - bf2f(h[j]));
    }
    *(uint4*)(hi + ob) = *(const uint4*)h;
    if (lo) *(uint4*)(lo + ob) = *(const uint4*)l;
}

// ---------------------------------------------------------------------------
// Pack Wv (B-operand: B[k][n]) -> pk[ks][ch][512(n)][8(k)] hi+lo
// ---------------------------------------------------------------------------
__global__ __launch_bounds__(256)
void pack_bT(const float* __restrict__ W, u16* __restrict__ hi, u16* __restrict__ lo)
{
    int idx = blockIdx.x * 256 + threadIdx.x;
    int n  = idx & (DIM - 1);
    int c8 = idx >> 9;
    int ks = c8 >> 2, ch = c8 & 3;
    size_t ob = ((size_t)(ks * 4 + ch) * DIM + n) * 8;
    u16 h[8], l[8];
#pragma unroll
    for (int j = 0; j < 8; j++) {
        float x = W[(size_t)(c8 * 8 + j) * DIM + n];
        h[j] = f2bf(x);
        l[j] = f2bf(x - bf2f(h[j]));
    }
    *(uint4*)(hi + ob) = *(const uint4*)h;
    *(uint4*)(lo + ob) = *(const uint4*)l;
}

// ---------------------------------------------------------------------------
// v = codebook @ Wv + bv  (bf16 hi/lo 3-pass MFMA, fp32 out), now with a
// 2-stage LDS double buffer: ks+1's loads are issued right after the barrier
// and fly while computing ks (the barrier's implicit vmcnt(0) drains them at
// the top of the next iteration).
// ---------------------------------------------------------------------------
__global__ __launch_bounds__(256, 2)
void mfma_v(const u16* __restrict__ Ah, const u16* __restrict__ Al,
            const u16* __restrict__ Bh, const u16* __restrict__ Bl,
            const float* __restrict__ bias, float* __restrict__ Cout)
{
    __shared__ u16 lds[2 * 16384];   // 2 stages x 4 arrays x 4096 u16 (64 KB)

    const int tid  = threadIdx.x;
    const int lane = tid & 63;
    const int wave = tid >> 6;
    const int wm = wave >> 1, wn = wave & 1;
    const int m0 = blockIdx.y * 128, n0 = blockIdx.x * 128;
    const int lr = lane & 15;
    const int q  = lane >> 4;

    f32x4 acc[4][4] = {};
    const u16* garr[4] = {Ah, Bh, Al, Bl};
    const int a = wave;                       // one array per wave
    const u16* src = garr[a];
    const bool isA = (a == 0 || a == 2);
    const int rb = isA ? m0 : n0;
    const size_t R = isA ? (size_t)VOC : (size_t)DIM;

#define VISSUE(ks, b)                                                         \
    {                                                                         \
        _Pragma("unroll")                                                     \
        for (int i_ = 0; i_ < 8; i_++) {                                      \
            const u16* gp_ = src + ((size_t)((ks) * 4 + (i_ >> 1)) * R + rb   \
                                    + (i_ & 1) * 64 + lane) * 8;              \
            async16(gp_, &lds[(b) * 16384 + a * 4096 + i_ * 512 + lane * 8]); \
        }                                                                     \
    }

    VISSUE(0, 0)

    for (int ks = 0; ks < 16; ks++) {
        __syncthreads();                       // drains vmcnt(0): stage ks in LDS
        if (ks < 15) VISSUE(ks + 1, (ks + 1) & 1)
        const u16* base = &lds[(ks & 1) * 16384];

        bf16x8 ah[4], al[4];
#pragma unroll
        for (int mt = 0; mt < 4; mt++) {
            int row = wm * 64 + mt * 16 + lr;
            ah[mt] = *(const bf16x8*)&base[0 * 4096 + q * 1024 + row * 8];
            al[mt] = *(const bf16x8*)&base[2 * 4096 + q * 1024 + row * 8];
        }
#pragma unroll
        for (int nt = 0; nt < 4; nt++) {
            int col = wn * 64 + nt * 16 + lr;
            bf16x8 bh = *(const bf16x8*)&base[1 * 4096 + q * 1024 + col * 8];
            bf16x8 bl = *(const bf16x8*)&base[3 * 4096 + q * 1024 + col * 8];
#pragma unroll
            for (int mt = 0; mt < 4; mt++) {
                acc[mt][nt] = __builtin_amdgcn_mfma_f32_16x16x32_bf16(ah[mt], bh, acc[mt][nt], 0, 0, 0);
                acc[mt][nt] = __builtin_amdgcn_mfma_f32_16x16x32_bf16(ah[mt], bl, acc[mt][nt], 0, 0, 0);
                acc[mt][nt] = __builtin_amdgcn_mfma_f32_16x16x32_bf16(al[mt], bh, acc[mt][nt], 0, 0, 0);
            }
        }
    }
#undef VISSUE

#pragma unroll
    for (int mt = 0; mt < 4; mt++)
#pragma unroll
        for (int nt = 0; nt < 4; nt++) {
            int col = n0 + wn * 64 + nt * 16 + lr;
            float bb = bias[col];
#pragma unroll
            for (int r = 0; r < 4; r++) {
                int rowg = m0 + wm * 64 + mt * 16 + q * 4 + r;
                Cout[(size_t)rowg * DIM + col] = acc[mt][nt][r] + bb;
            }
        }
}

// ---------------------------------------------------------------------------
// Fused dots GEMM v3: 3-stage pipeline (vmcnt(4): next stage's loads stay in
// flight across the raw barrier) + M-FASTEST block order — concurrent blocks
// span all 32 m-tiles x a narrow sliding n-window, so every cbh line's 32
// reuses land while it is L2/L3-resident (q2h 4MB stays L3-hot all kernel).
// Epilogue appends candidates (val >= trow[row]); dots never stored.
// ---------------------------------------------------------------------------
__global__ __launch_bounds__(256, 2)
void mfma_dots(const u16* __restrict__ Ah, const u16* __restrict__ Bh,
               const float* __restrict__ trow, unsigned* __restrict__ candBuf,
               unsigned* __restrict__ counters)
{
    __shared__ u16 lds[3 * 8192];      // 3 stages x (A 4096 + B 4096) u16

    const int tid  = threadIdx.x;
    const int lane = tid & 63;
    const int wave = tid >> 6;
    const int wm = wave >> 1, wn = wave & 1;
    const int lr = lane & 15;
    const int q  = lane >> 4;

    // m-fastest ordering: L&31 = m-tile, L>>5 = n-tile.
    const int L  = blockIdx.x;
    const int m0 = (L & 31) * 128;
    const int n0 = (L >> 5) * 128;

    const int a  = wave >> 1;                  // 0: stage A (q2h), 1: stage B (cbh)
    const u16* src = a ? Bh : Ah;
    const int rb   = a ? n0 : m0;
    const size_t R = a ? (size_t)VOC : (size_t)BATCH;
    const int i0   = (wave & 1) * 4;

    f32x4 acc[4][4] = {};

#define ISSUE(ks, b)                                                          \
    {                                                                         \
        _Pragma("unroll")                                                     \
        for (int s_ = 0; s_ < 4; s_++) {                                      \
            int i_ = i0 + s_;                                                 \
            const u16* gp_ = src + ((size_t)((ks) * 4 + (i_ >> 1)) * R + rb   \
                                    + (i_ & 1) * 64 + lane) * 8;              \
            async16(gp_, &lds[(b) * 8192 + a * 4096 + i_ * 512 + lane * 8]);  \
        }                                                                     \
    }

    ISSUE(0, 0)
    ISSUE(1, 1)

    for (int s = 0; s < 16; s++) {
        // wait for stage s only (stage s+1's 4 loads keep flying); raw barrier
        if (s == 15) __builtin_amdgcn_s_waitcnt(0x0F70);   // vmcnt(0)
        else         __builtin_amdgcn_s_waitcnt(0x0F74);   // vmcnt(4)
        __builtin_amdgcn_s_barrier();
        if (s < 14) {
            int b2 = (s + 2) % 3;
            ISSUE(s + 2, b2)
        }
        const u16* base = &lds[(s % 3) * 8192];

        bf16x8 ah[4];
#pragma unroll
        for (int mt = 0; mt < 4; mt++)
            ah[mt] = *(const bf16x8*)&base[q * 1024 + (wm * 64 + mt * 16 + lr) * 8];
#pragma unroll
        for (int nt = 0; nt < 4; nt++) {
            bf16x8 bh = *(const bf16x8*)&base[4096 + q * 1024 + (wn * 64 + nt * 16 + lr) * 8];
#pragma unroll
            for (int mt = 0; mt < 4; mt++)
                acc[mt][nt] = __builtin_amdgcn_mfma_f32_16x16x32_bf16(ah[mt], bh, acc[mt][nt], 0, 0, 0);
        }
    }
#undef ISSUE

    // epilogue: threshold-append candidates
#pragma unroll
    for (int mt = 0; mt < 4; mt++) {
#pragma unroll
        for (int r = 0; r < 4; r++) {
            int rowg = m0 + wm * 64 + mt * 16 + q * 4 + r;
            float tr = trow[rowg];
#pragma unroll
            for (int nt = 0; nt < 4; nt++) {
                float val = acc[mt][nt][r];
                if (val >= tr) {
                    unsigned slot = atomicAdd(&counters[rowg], 1u);
                    if (slot < CAND_CAP) {
                        unsigned s16 = enc16(f2bf(val));
                        candBuf[(size_t)rowg * CAND_CAP + slot] =
                            (s16 << 16) | (unsigned)(n0 + wn * 64 + nt * 16 + lr);
                    }
                }
            }
        }
    }
}

// ---------------------------------------------------------------------------
// Select v5: sort candidates by approx -> verify t <= a64 - 2*EPS (proof of
// top-64 coverage) -> fp64 rescue of band -> exact sort -> thresh (ties) ->
// softmax -> out_row = sum w_i * v[idx_i].  Anomalies -> flags (fallback).
// ---------------------------------------------------------------------------
__global__ __launch_bounds__(256)
void select5(const unsigned* __restrict__ candBuf, const unsigned* __restrict__ counters,
             const float* __restrict__ trow, const float* __restrict__ q2,
             const float* __restrict__ codebook, const float* __restrict__ v,
             float* __restrict__ out, unsigned* __restrict__ flags)
{
    __shared__ unsigned recs[CAND_CAP];
    __shared__ unsigned long long keys[RES_CAP];
    __shared__ float q2s[DIM];
    __shared__ float wArr[RES_CAP];
    __shared__ float redf[256];
    __shared__ unsigned redu[256];
    __shared__ unsigned s_R;

    const int tid  = threadIdx.x;
    const int lane = tid & 63;
    const int wave = tid >> 6;
    const int row  = blockIdx.x;

    const unsigned cnt = counters[row];
    if (cnt < TOPK || cnt > CAND_CAP) {
        if (tid == 0) flags[row] = 1u;
        return;
    }
    for (int i = tid; i < DIM; i += 256) q2s[i] = q2[(size_t)row * DIM + i];
    for (int i = tid; i < CAND_CAP; i += 256)
        recs[i] = (i < (int)cnt) ? candBuf[(size_t)row * CAND_CAP + i] : 0u;
    if (tid == 0) s_R = 0;
    __syncthreads();

    // bitonic sort 512 u32 DESCENDING (sortkey high 16 bits; pads=0 last)
    for (int k = 2; k <= CAND_CAP; k <<= 1) {
        for (int j = k >> 1; j > 0; j >>= 1) {
#pragma unroll
            for (int e = 0; e < 2; e++) {
                int i = tid + e * 256;
                int ixj = i ^ j;
                if (ixj > i) {
                    unsigned a = recs[i], b = recs[ixj];
                    if (((i & k) == 0) ? (a < b) : (a > b)) { recs[i] = b; recs[ixj] = a; }
                }
            }
            __syncthreads();
        }
    }

    const float a64  = dec16(recs[TOPK - 1] >> 16);
    const float band = a64 - 2.f * EPS_SEL;
    if (trow[row] > band) {
        if (tid == 0) flags[row] = 1u;
        return;
    }

#pragma unroll
    for (int e = 0; e < 2; e++) {
        int i = tid + e * 256;
        if (i < (int)cnt && dec16(recs[i] >> 16) >= band) atomicAdd(&s_R, 1u);
    }
    __syncthreads();
    const int R = (int)s_R;
    if (R > RES_CAP) {
        if (tid == 0) flags[row] = 1u;
        return;
    }

    // fp64 rescue: wave per candidate, coalesced codebook reads
    for (int c = wave; c < R; c += 4) {
        unsigned idx = recs[c] & 0xFFFFu;
        const float* cb = codebook + (size_t)idx * DIM + lane * 8;
        float4 c0 = *(const float4*)cb, c1 = *(const float4*)(cb + 4);
        const float* qp = &q2s[lane * 8];
        float4 a0 = *(const float4*)qp, a1 = *(const float4*)(qp + 4);
        double s = (double)a0.x * c0.x + (double)a0.y * c0.y
                 + (double)a0.z * c0.z + (double)a0.w * c0.w
                 + (double)a1.x * c1.x + (double)a1.y * c1.y
                 + (double)a1.z * c1.z + (double)a1.w * c1.w;
#pragma unroll
        for (int off = 32; off > 0; off >>= 1) s += __shfl_down(s, off);
        if (lane == 0) {
            float val = (float)s;
            unsigned b = __float_as_uint(val);
            unsigned sk = (b & 0x80000000u) ? ~b : (b | 0x80000000u);
            keys[c] = ((unsigned long long)(~sk) << 32) | idx;
        }
    }
    if (tid >= R && tid < RES_CAP) keys[tid] = ~0ULL;
    __syncthreads();

    // bitonic sort 256 u64 ascending (= descending by exact value)
    for (int k = 2; k <= RES_CAP; k <<= 1) {
        for (int j = k >> 1; j > 0; j >>= 1) {
            int ixj = tid ^ j;
            if (ixj > tid) {
                unsigned long long a = keys[tid], b2 = keys[ixj];
                if (((tid & k) == 0) ? (a > b2) : (a < b2)) { keys[tid] = b2; keys[ixj] = a; }
            }
            __syncthreads();
        }
    }

    const unsigned threshInv = (unsigned)(keys[TOPK - 1] >> 32);
    unsigned sk0 = ~(unsigned)(keys[0] >> 32);
    const float vmax = __uint_as_float((sk0 & 0x80000000u) ? (sk0 & 0x7FFFFFFFu) : ~sk0);

    unsigned hi = (unsigned)(keys[tid] >> 32);
    bool sel = (hi <= threshInv);
    unsigned sk = ~hi;
    float val = __uint_as_float((sk & 0x80000000u) ? (sk & 0x7FFFFFFFu) : ~sk);
    float w = sel ? expf(val - vmax) : 0.f;
    wArr[tid] = w;
    redf[tid] = w;
    redu[tid] = sel ? 1u : 0u;
    __syncthreads();
    for (int s = 128; s > 0; s >>= 1) {
        if (tid < s) { redf[tid] += redf[tid + s]; redu[tid] += redu[tid + s]; }
        __syncthreads();
    }
    const float invZ = 1.0f / redf[0];
    const int selCount = (int)redu[0];

    for (int d = tid; d < DIM; d += 256) {
        float acc = 0.f;
        for (int i = 0; i < selCount; i++) {
            unsigned idx = (unsigned)(keys[i] & 0xFFFFFFFFu);
            acc += wArr[i] * v[(size_t)idx * DIM + d];
        }
        out[(size_t)row * DIM + d] = acc * invZ;
    }
}

// ---------------------------------------------------------------------------
// Exact fallback for flagged rows (expected: none). fp64 scan over all VOC.
// ---------------------------------------------------------------------------
__global__ __launch_bounds__(256)
void fallback_row(const unsigned* __restrict__ flags, const float* __restrict__ q2,
                  const float* __restrict__ codebook, const float* __restrict__ v,
                  const float* __restrict__ trow, const float* __restrict__ sigrow,
                  float* __restrict__ out)
{
    const int row = blockIdx.x;
    if (!flags[row]) return;

    __shared__ float q2s[DIM];
    __shared__ unsigned long long keys[FCAP];
    __shared__ float wArr[FCAP];
    __shared__ float redf[256];
    __shared__ unsigned redu[256];
    __shared__ unsigned s_cnt;

    const int tid = threadIdx.x;
    for (int i = tid; i < DIM; i += 256) q2s[i] = q2[(size_t)row * DIM + i];
    const float sig = sigrow[row];
    float tf = trow[row] - 0.35f * sig;
    unsigned cnt = 0;

    for (int it = 0; it < 16; it++) {
        if (tid == 0) s_cnt = 0;
        __syncthreads();
        for (int i = tid; i < VOC; i += 256) {
            const float* cb = codebook + (size_t)i * DIM;
            double s = 0.0;
            for (int d = 0; d < DIM; d += 4) {
                float4 c4 = *(const float4*)(cb + d);
                s += (double)q2s[d + 0] * (double)c4.x + (double)q2s[d + 1] * (double)c4.y
                   + (double)q2s[d + 2] * (double)c4.z + (double)q2s[d + 3] * (double)c4.w;
            }
            float vv = (float)s;
            if (vv >= tf) {
                unsigned p = atomicAdd(&s_cnt, 1u);
                if (p < FCAP) {
                    unsigned b = __float_as_uint(vv);
                    unsigned sk = (b & 0x80000000u) ? ~b : (b | 0x80000000u);
                    keys[p] = ((unsigned long long)(~sk) << 32) | (unsigned)i;
                }
            }
        }
        __syncthreads();
        cnt = s_cnt;
        if (cnt > FCAP) { tf += 0.15f * sig; continue; }
        if (cnt < TOPK) { tf -= 0.35f * sig; continue; }
        break;
    }
    if (cnt > FCAP) cnt = FCAP;
    for (int i = tid; i < FCAP; i += 256)
        if (i >= (int)cnt) keys[i] = ~0ULL;
    __syncthreads();

    for (int k = 2; k <= FCAP; k <<= 1) {
        for (int j = k >> 1; j > 0; j >>= 1) {
#pragma unroll
            for (int e = 0; e < 4; e++) {
                int i = tid + e * 256;
                int ixj = i ^ j;
                if (ixj > i) {
                    unsigned long long a = keys[i], b = keys[ixj];
                    if (((i & k) == 0) ? (a > b) : (a < b)) { keys[i] = b; keys[ixj] = a; }
                }
            }
            __syncthreads();
        }
    }

    const unsigned threshInv = (unsigned)(keys[TOPK - 1] >> 32);
    unsigned sk0 = ~(unsigned)(keys[0] >> 32);
    const float vmax = __uint_as_float((sk0 & 0x80000000u) ? (sk0 & 0x7FFFFFFFu) : ~sk0);

    float lsum = 0.f; unsigned lcnt = 0;
    for (int i = tid; i < FCAP; i += 256) {
        unsigned hi = (unsigned)(keys[i] >> 32);
        bool sel = (hi <= threshInv);
        unsigned sk = ~hi;
        float vv = __uint_as_float((sk & 0x80000000u) ? (sk & 0x7FFFFFFFu) : ~sk);
        float w = sel ? expf(vv - vmax) : 0.f;
        wArr[i] = w;
        lsum += w; lcnt += sel ? 1u : 0u;
    }
    redf[tid] = lsum; redu[tid] = lcnt;
    __syncthreads();
    for (int s = 128; s > 0; s >>= 1) {
        if (tid < s) { redf[tid] += redf[tid + s]; redu[tid] += redu[tid + s]; }
        __syncthreads();
    }
    const float invZ = 1.f / redf[0];
    const int selCount = (int)redu[0];

    for (int d = tid; d < DIM; d += 256) {
        float acc = 0.f;
        for (int i = 0; i < selCount; i++) {
            unsigned idx = (unsigned)(keys[i] & 0xFFFFFFFFu);
            acc += wArr[i] * v[(size_t)idx * DIM + d];
        }
        out[(size_t)row * DIM + d] = acc * invZ;
    }
}

// ---------------------------------------------------------------------------
extern "C" void kernel_launch(void* const* d_in, const int* in_sizes, int n_in,
                              void* d_out, int out_size, void* d_ws, size_t ws_size,
                              hipStream_t stream)
{
    const float* x        = (const float*)d_in[0];
    const float* codebook = (const float*)d_in[1];
    const float* Wq       = (const float*)d_in[2];
    const float* bq       = (const float*)d_in[3];
    const float* Wk       = (const float*)d_in[4];
    // d_in[5] = bk: per-row-constant shift in dots (top-k & softmax invariant)
    const float* Wv       = (const float*)d_in[6];
    const float* bv       = (const float*)d_in[7];
    float* out = (float*)d_out;

    // workspace (~150 MB)
    float* q2   = (float*)d_ws;                       // 4096x512   (8 MB)
    float* Wqk  = q2   + (size_t)BATCH * DIM;         // 512x512    (1 MB)
    float* bqk  = Wqk  + (size_t)DIM * DIM;           // 512 (pad 1024)
    float* v    = bqk  + 1024;                        // 32768x512  (64 MB)
    float* trow = v    + (size_t)VOC * DIM;           // 4096
    float* sigr = trow + BATCH;                       // 4096
    unsigned* counters = (unsigned*)(sigr + BATCH);   // 4096
    unsigned* flags    = counters + BATCH;            // 4096
    float* cbarsum     = (float*)(flags + BATCH);     // 512
    unsigned* candBuf  = (unsigned*)(cbarsum + 512);  // 4096x512 (8 MB)
    u16* q2h = (u16*)(candBuf + (size_t)BATCH * CAND_CAP);   // 4 MB
    u16* cbh = q2h + (size_t)BATCH * DIM;                    // 32 MB
    u16* cbl = cbh + (size_t)VOC * DIM;                      // 32 MB
    u16* wvh = cbl + (size_t)VOC * DIM;                      // 0.5 MB
    u16* wvl = wvh + (size_t)DIM * DIM;                      // 0.5 MB

    dim3 blk(256);

    // zero counters+flags+cbarsum (contiguous 8704 words)
    zero_ws<<<dim3(34), blk, 0, stream>>>(counters, BATCH * 2 + 512);

    // Wqk = Wq @ Wk^T ; bqk = bq @ Wk^T ; q2 = x @ Wqk + bqk (selection-critical)
    gemm64<true, true><<<dim3(DIM / 64, DIM / 64), blk, 0, stream>>>(
        Wq, Wk, nullptr, Wqk, DIM, DIM, DIM);
    bias_fold<<<dim3(2), blk, 0, stream>>>(bq, Wk, bqk);
    gemm64<false, true><<<dim3(DIM / 64, BATCH / 64), blk, 0, stream>>>(
        x, Wqk, bqk, q2, BATCH, DIM, DIM);

    // analytic per-row candidate threshold
    cbar_accum<<<dim3(VOC / 512), blk, 0, stream>>>(codebook, cbarsum);
    rowstats<<<dim3(BATCH / 4), blk, 0, stream>>>(q2, cbarsum, trow, sigr);

    // pack MFMA operands
    pack_rows<<<dim3(BATCH * 64 / 256), blk, 0, stream>>>(q2, q2h, nullptr, BATCH, 12);
    pack_rows<<<dim3(VOC * 64 / 256), blk, 0, stream>>>(codebook, cbh, cbl, VOC, 15);
    pack_bT<<<dim3(DIM * 64 / 256), blk, 0, stream>>>(Wv, wvh, wvl);

    // fused dots GEMM (pipelined, m-fastest locality order) + candidate append
    mfma_dots<<<dim3(8192), blk, 0, stream>>>(q2h, cbh, trow, candBuf, counters);

    // v = codebook @ Wv + bv (hi/lo 3-pass MFMA, double-buffered)
    mfma_v<<<dim3(DIM / 128, VOC / 128), blk, 0, stream>>>(cbh, cbl, wvh, wvl, bv, v);

    // exact selection + softmax + out = attn @ v
    select5<<<dim3(BATCH), blk, 0, stream>>>(
        candBuf, counters, trow, q2, codebook, v, out, flags);
    fallback_row<<<dim3(BATCH), blk, 0, stream>>>(
        flags, q2, codebook, v, trow, sigr, out);
}

// Round 8
// 758.336 us; speedup vs baseline: 1.3572x; 1.0342x over previous
//
#include <hip/hip_runtime.h>
#include <cstdint>

#define VOC   32768
#define DIM   512
#define TOPK  64
#define BATCH 4096

#define KSIG     2.45f
#define EPS_SEL  0.012f
#define CAND_CAP 512
#define RES_CAP  256
#define FCAP     1024

typedef unsigned short u16;
typedef __attribute__((ext_vector_type(8))) short bf16x8;
typedef __attribute__((ext_vector_type(4))) float f32x4;

// ---- bf16 helpers (RNE) ----------------------------------------------------
__device__ __forceinline__ u16 f2bf(float f) {
    unsigned u = __float_as_uint(f);
    unsigned r = (u + 0x7FFFu + ((u >> 16) & 1u)) >> 16;
    return (u16)r;
}
__device__ __forceinline__ float bf2f(u16 h) {
    return __uint_as_float(((unsigned)h) << 16);
}
__device__ __forceinline__ unsigned enc16(u16 h) {
    return (h & 0x8000u) ? (unsigned)((u16)~h) : (unsigned)(h | 0x8000u);
}
__device__ __forceinline__ float dec16(unsigned s16) {
    u16 h = (s16 & 0x8000u) ? (u16)(s16 ^ 0x8000u) : (u16)(~s16);
    return bf2f(h);
}

// ---- async global->LDS 16B -------------------------------------------------
__device__ __forceinline__ void async16(const void* g, void* l) {
    __builtin_amdgcn_global_load_lds(
        (const __attribute__((address_space(1))) void*)g,
        (__attribute__((address_space(3))) void*)l, 16, 0, 0);
}

// ---------------------------------------------------------------------------
// fp32 64x64-tile GEMM + optional per-k-tile fp64 flush. 256 thr, 4x4 micro.
//   BT=false: C = A(MxK) @ B(KxN) (+bias);  BT=true: C = A @ B^T (B NxK)
// ---------------------------------------------------------------------------
template <bool BT, bool F64ACC>
__global__ __launch_bounds__(256)
void gemm64(const float* __restrict__ A, const float* __restrict__ B,
            const float* __restrict__ bias, float* __restrict__ C,
            int M, int N, int K)
{
    const int KS = 16;
    __shared__ float As[KS][68];
    __shared__ float Bs[KS][64];

    const int tid = threadIdx.x;
    const int m0 = blockIdx.y * 64;
    const int n0 = blockIdx.x * 64;
    const int ty = tid >> 4;
    const int tx = tid & 15;

    float acc[4][4];
    double acc64[4][4];
#pragma unroll
    for (int i = 0; i < 4; i++)
#pragma unroll
        for (int j = 0; j < 4; j++) { acc[i][j] = 0.f; if (F64ACC) acc64[i][j] = 0.0; }

    for (int kt = 0; kt < K; kt += KS) {
        {
            int row = tid >> 2, kq = tid & 3;
            const float4 av = *(const float4*)(A + (size_t)(m0 + row) * K + kt + kq * 4);
            As[kq * 4 + 0][row] = av.x;
            As[kq * 4 + 1][row] = av.y;
            As[kq * 4 + 2][row] = av.z;
            As[kq * 4 + 3][row] = av.w;
        }
        if (!BT) {
            int krow = tid >> 4, nq = tid & 15;
            *(float4*)&Bs[krow][nq * 4] =
                *(const float4*)(B + (size_t)(kt + krow) * N + n0 + nq * 4);
        } else {
            int nrow = tid >> 2, kq = tid & 3;
            const float4 bv = *(const float4*)(B + (size_t)(n0 + nrow) * K + kt + kq * 4);
            Bs[kq * 4 + 0][nrow] = bv.x;
            Bs[kq * 4 + 1][nrow] = bv.y;
            Bs[kq * 4 + 2][nrow] = bv.z;
            Bs[kq * 4 + 3][nrow] = bv.w;
        }
        __syncthreads();

#pragma unroll
        for (int kk = 0; kk < KS; kk++) {
            float4 a = *(const float4*)&As[kk][ty * 4];
            float4 b = *(const float4*)&Bs[kk][tx * 4];
            float av[4] = {a.x, a.y, a.z, a.w};
            float bv[4] = {b.x, b.y, b.z, b.w};
#pragma unroll
            for (int i = 0; i < 4; i++)
#pragma unroll
                for (int j = 0; j < 4; j++)
                    acc[i][j] += av[i] * bv[j];
        }
        __syncthreads();
        if (F64ACC) {
#pragma unroll
            for (int i = 0; i < 4; i++)
#pragma unroll
                for (int j = 0; j < 4; j++) { acc64[i][j] += (double)acc[i][j]; acc[i][j] = 0.f; }
        }
    }

    float4 bb = make_float4(0.f, 0.f, 0.f, 0.f);
    if (bias) bb = *(const float4*)(bias + n0 + tx * 4);
#pragma unroll
    for (int i = 0; i < 4; i++) {
        float4 o;
        o.x = (F64ACC ? (float)acc64[i][0] : acc[i][0]) + bb.x;
        o.y = (F64ACC ? (float)acc64[i][1] : acc[i][1]) + bb.y;
        o.z = (F64ACC ? (float)acc64[i][2] : acc[i][2]) + bb.z;
        o.w = (F64ACC ? (float)acc64[i][3] : acc[i][3]) + bb.w;
        *(float4*)(C + (size_t)(m0 + ty * 4 + i) * N + n0 + tx * 4) = o;
    }
}

// ---------------------------------------------------------------------------
__global__ void bias_fold(const float* __restrict__ bq, const float* __restrict__ Wk,
                          float* __restrict__ bqk)
{
    int j = blockIdx.x * 256 + threadIdx.x;
    if (j >= DIM) return;
    double s = 0.0;
    const float* wr = Wk + (size_t)j * DIM;
    for (int d = 0; d < DIM; d++) s += (double)bq[d] * (double)wr[d];
    bqk[j] = (float)s;
}

__global__ void zero_ws(unsigned* __restrict__ p, int n)
{
    int i = blockIdx.x * 256 + threadIdx.x;
    if (i < n) p[i] = 0u;
}

// ---------------------------------------------------------------------------
// Column sums of codebook (for mu_row). 256 blocks x 128 rows.
// ---------------------------------------------------------------------------
__global__ __launch_bounds__(256)
void cbar_accum(const float* __restrict__ cb, float* __restrict__ cbarsum)
{
    const int tid = threadIdx.x;
    const int r0 = blockIdx.x * 128;
    float s0 = 0.f, s1 = 0.f;
    for (int r = 0; r < 128; r++) {
        const float* rp = cb + (size_t)(r0 + r) * DIM;
        s0 += rp[tid];
        s1 += rp[tid + 256];
    }
    atomicAdd(&cbarsum[tid], s0);
    atomicAdd(&cbarsum[tid + 256], s1);
}

// ---------------------------------------------------------------------------
// Per-row analytic threshold: t = mu + KSIG*sigma, sigma = ||q2_row||/sqrt(1536).
// ---------------------------------------------------------------------------
__global__ __launch_bounds__(256)
void rowstats(const float* __restrict__ q2, const float* __restrict__ cbarsum,
              float* __restrict__ trow, float* __restrict__ sigrow)
{
    const int tid = threadIdx.x, lane = tid & 63, wave = tid >> 6;
    const int row = blockIdx.x * 4 + wave;
    const float* qp = q2 + (size_t)row * DIM + lane * 8;
    float4 a0 = *(const float4*)qp, a1 = *(const float4*)(qp + 4);
    const float* cp = cbarsum + lane * 8;
    float4 c0 = *(const float4*)cp, c1 = *(const float4*)(cp + 4);
    float mu = a0.x*c0.x + a0.y*c0.y + a0.z*c0.z + a0.w*c0.w
             + a1.x*c1.x + a1.y*c1.y + a1.z*c1.z + a1.w*c1.w;
    float nr = a0.x*a0.x + a0.y*a0.y + a0.z*a0.z + a0.w*a0.w
             + a1.x*a1.x + a1.y*a1.y + a1.z*a1.z + a1.w*a1.w;
#pragma unroll
    for (int off = 32; off > 0; off >>= 1) {
        mu += __shfl_down(mu, off);
        nr += __shfl_down(nr, off);
    }
    if (lane == 0) {
        mu *= (1.f / VOC);
        float sig = sqrtf(nr * (1.f / 1536.f));
        trow[row] = mu + KSIG * sig;
        sigrow[row] = sig;
    }
}

// ---------------------------------------------------------------------------
// Pack fp32 [R x 512] -> MFMA operand layout pk[ks][ch][R][8] bf16.
// ---------------------------------------------------------------------------
__global__ __launch_bounds__(256)
void pack_rows(const float* __restrict__ src, u16* __restrict__ hi,
               int R, int log2R)
{
    int idx = blockIdx.x * 256 + threadIdx.x;
    int c8  = idx >> log2R;
    int row = idx & (R - 1);
    const float* sp = src + (size_t)row * DIM + c8 * 8;
    float xv[8];
    *(float4*)&xv[0] = *(const float4*)sp;
    *(float4*)&xv[4] = *(const float4*)(sp + 4);
    int ks = c8 >> 2, ch = c8 & 3;
    size_t ob = ((size_t)(ks * 4 + ch) * R + row) * 8;
    u16 h[8];
#pragma unroll
    for (int j = 0; j < 8; j++) h[j] = f2bf(xv[j]);
    *(uint4*)(hi + ob) = *(const uint4*)h;
}

// ---------------------------------------------------------------------------
// Fused dots GEMM v4: 3-stage pipeline (vmcnt(4) keeps next stage's loads in
// flight across the raw barrier) + m-fastest block order (round-7 win) +
// 3 blocks/CU (LDS 48KBx3=144KB). Epilogue appends candidates (>= trow[row]).
// ---------------------------------------------------------------------------
__global__ __launch_bounds__(256, 3)
void mfma_dots(const u16* __restrict__ Ah, const u16* __restrict__ Bh,
               const float* __restrict__ trow, unsigned* __restrict__ candBuf,
               unsigned* __restrict__ counters)
{
    __shared__ u16 lds[3 * 8192];      // 3 stages x (A 4096 + B 4096) u16

    const int tid  = threadIdx.x;
    const int lane = tid & 63;
    const int wave = tid >> 6;
    const int wm = wave >> 1, wn = wave & 1;
    const int lr = lane & 15;
    const int q  = lane >> 4;

    // m-fastest ordering: L&31 = m-tile, L>>5 = n-tile.
    const int L  = blockIdx.x;
    const int m0 = (L & 31) * 128;
    const int n0 = (L >> 5) * 128;

    const int a  = wave >> 1;                  // 0: stage A (q2h), 1: stage B (cbh)
    const u16* src = a ? Bh : Ah;
    const int rb   = a ? n0 : m0;
    const size_t R = a ? (size_t)VOC : (size_t)BATCH;
    const int i0   = (wave & 1) * 4;

    f32x4 acc[4][4] = {};

#define ISSUE(ks, b)                                                          \
    {                                                                         \
        _Pragma("unroll")                                                     \
        for (int s_ = 0; s_ < 4; s_++) {                                      \
            int i_ = i0 + s_;                                                 \
            const u16* gp_ = src + ((size_t)((ks) * 4 + (i_ >> 1)) * R + rb   \
                                    + (i_ & 1) * 64 + lane) * 8;              \
            async16(gp_, &lds[(b) * 8192 + a * 4096 + i_ * 512 + lane * 8]);  \
        }                                                                     \
    }

    ISSUE(0, 0)
    ISSUE(1, 1)

    for (int s = 0; s < 16; s++) {
        if (s == 15) __builtin_amdgcn_s_waitcnt(0x0F70);   // vmcnt(0)
        else         __builtin_amdgcn_s_waitcnt(0x0F74);   // vmcnt(4)
        __builtin_amdgcn_s_barrier();
        if (s < 14) {
            int b2 = (s + 2) % 3;
            ISSUE(s + 2, b2)
        }
        const u16* base = &lds[(s % 3) * 8192];

        bf16x8 ah[4];
#pragma unroll
        for (int mt = 0; mt < 4; mt++)
            ah[mt] = *(const bf16x8*)&base[q * 1024 + (wm * 64 + mt * 16 + lr) * 8];
#pragma unroll
        for (int nt = 0; nt < 4; nt++) {
            bf16x8 bh = *(const bf16x8*)&base[4096 + q * 1024 + (wn * 64 + nt * 16 + lr) * 8];
#pragma unroll
            for (int mt = 0; mt < 4; mt++)
                acc[mt][nt] = __builtin_amdgcn_mfma_f32_16x16x32_bf16(ah[mt], bh, acc[mt][nt], 0, 0, 0);
        }
    }
#undef ISSUE

    // epilogue: threshold-append candidates
#pragma unroll
    for (int mt = 0; mt < 4; mt++) {
#pragma unroll
        for (int r = 0; r < 4; r++) {
            int rowg = m0 + wm * 64 + mt * 16 + q * 4 + r;
            float tr = trow[rowg];
#pragma unroll
            for (int nt = 0; nt < 4; nt++) {
                float val = acc[mt][nt][r];
                if (val >= tr) {
                    unsigned slot = atomicAdd(&counters[rowg], 1u);
                    if (slot < CAND_CAP) {
                        unsigned s16 = enc16(f2bf(val));
                        candBuf[(size_t)rowg * CAND_CAP + slot] =
                            (s16 << 16) | (unsigned)(n0 + wn * 64 + nt * 16 + lr);
                    }
                }
            }
        }
    }
}

// ---------------------------------------------------------------------------
// Select v6: sort candidates by approx -> verify t <= a64 - 2*EPS (proof of
// top-64 coverage) -> fp64 rescue of band -> exact sort -> thresh (ties) ->
// softmax -> y_row = sum w_i * codebook[idx_i] (rows L2-hot from the rescue).
// out = y @ Wv + bv happens in a later gemm64 (linearity: sum w = 1).
// ---------------------------------------------------------------------------
__global__ __launch_bounds__(256)
void select6(const unsigned* __restrict__ candBuf, const unsigned* __restrict__ counters,
             const float* __restrict__ trow, const float* __restrict__ q2,
             const float* __restrict__ codebook, float* __restrict__ y,
             unsigned* __restrict__ flags)
{
    __shared__ unsigned recs[CAND_CAP];
    __shared__ unsigned long long keys[RES_CAP];
    __shared__ float q2s[DIM];
    __shared__ float wArr[RES_CAP];
    __shared__ float redf[256];
    __shared__ unsigned redu[256];
    __shared__ unsigned s_R;

    const int tid  = threadIdx.x;
    const int lane = tid & 63;
    const int wave = tid >> 6;
    const int row  = blockIdx.x;

    const unsigned cnt = counters[row];
    if (cnt < TOPK || cnt > CAND_CAP) {
        if (tid == 0) flags[row] = 1u;
        return;
    }
    for (int i = tid; i < DIM; i += 256) q2s[i] = q2[(size_t)row * DIM + i];
    for (int i = tid; i < CAND_CAP; i += 256)
        recs[i] = (i < (int)cnt) ? candBuf[(size_t)row * CAND_CAP + i] : 0u;
    if (tid == 0) s_R = 0;
    __syncthreads();

    // bitonic sort 512 u32 DESCENDING (sortkey high 16 bits; pads=0 last)
    for (int k = 2; k <= CAND_CAP; k <<= 1) {
        for (int j = k >> 1; j > 0; j >>= 1) {
#pragma unroll
            for (int e = 0; e < 2; e++) {
                int i = tid + e * 256;
                int ixj = i ^ j;
                if (ixj > i) {
                    unsigned a = recs[i], b = recs[ixj];
                    if (((i & k) == 0) ? (a < b) : (a > b)) { recs[i] = b; recs[ixj] = a; }
                }
            }
            __syncthreads();
        }
    }

    const float a64  = dec16(recs[TOPK - 1] >> 16);
    const float band = a64 - 2.f * EPS_SEL;
    if (trow[row] > band) {
        if (tid == 0) flags[row] = 1u;
        return;
    }

#pragma unroll
    for (int e = 0; e < 2; e++) {
        int i = tid + e * 256;
        if (i < (int)cnt && dec16(recs[i] >> 16) >= band) atomicAdd(&s_R, 1u);
    }
    __syncthreads();
    const int R = (int)s_R;
    if (R > RES_CAP) {
        if (tid == 0) flags[row] = 1u;
        return;
    }

    // fp64 rescue: wave per candidate, coalesced codebook reads
    for (int c = wave; c < R; c += 4) {
        unsigned idx = recs[c] & 0xFFFFu;
        const float* cb = codebook + (size_t)idx * DIM + lane * 8;
        float4 c0 = *(const float4*)cb, c1 = *(const float4*)(cb + 4);
        const float* qp = &q2s[lane * 8];
        float4 a0 = *(const float4*)qp, a1 = *(const float4*)(qp + 4);
        double s = (double)a0.x * c0.x + (double)a0.y * c0.y
                 + (double)a0.z * c0.z + (double)a0.w * c0.w
                 + (double)a1.x * c1.x + (double)a1.y * c1.y
                 + (double)a1.z * c1.z + (double)a1.w * c1.w;
#pragma unroll
        for (int off = 32; off > 0; off >>= 1) s += __shfl_down(s, off);
        if (lane == 0) {
            float val = (float)s;
            unsigned b = __float_as_uint(val);
            unsigned sk = (b & 0x80000000u) ? ~b : (b | 0x80000000u);
            keys[c] = ((unsigned long long)(~sk) << 32) | idx;
        }
    }
    if (tid >= R && tid < RES_CAP) keys[tid] = ~0ULL;
    __syncthreads();

    // bitonic sort 256 u64 ascending (= descending by exact value)
    for (int k = 2; k <= RES_CAP; k <<= 1) {
        for (int j = k >> 1; j > 0; j >>= 1) {
            int ixj = tid ^ j;
            if (ixj > tid) {
                unsigned long long a = keys[tid], b2 = keys[ixj];
                if (((tid & k) == 0) ? (a > b2) : (a < b2)) { keys[tid] = b2; keys[ixj] = a; }
            }
            __syncthreads();
        }
    }

    const unsigned threshInv = (unsigned)(keys[TOPK - 1] >> 32);
    unsigned sk0 = ~(unsigned)(keys[0] >> 32);
    const float vmax = __uint_as_float((sk0 & 0x80000000u) ? (sk0 & 0x7FFFFFFFu) : ~sk0);

    unsigned hi = (unsigned)(keys[tid] >> 32);
    bool sel = (hi <= threshInv);
    unsigned sk = ~hi;
    float val = __uint_as_float((sk & 0x80000000u) ? (sk & 0x7FFFFFFFu) : ~sk);
    float w = sel ? expf(val - vmax) : 0.f;
    wArr[tid] = w;
    redf[tid] = w;
    redu[tid] = sel ? 1u : 0u;
    __syncthreads();
    for (int s = 128; s > 0; s >>= 1) {
        if (tid < s) { redf[tid] += redf[tid + s]; redu[tid] += redu[tid + s]; }
        __syncthreads();
    }
    const float invZ = 1.0f / redf[0];
    const int selCount = (int)redu[0];

    // y_row = sum_i w_i * codebook[idx_i, :]
    for (int d = tid; d < DIM; d += 256) {
        float acc = 0.f;
        for (int i = 0; i < selCount; i++) {
            unsigned idx = (unsigned)(keys[i] & 0xFFFFFFFFu);
            acc += wArr[i] * codebook[(size_t)idx * DIM + d];
        }
        y[(size_t)row * DIM + d] = acc * invZ;
    }
}

// ---------------------------------------------------------------------------
// Exact fallback for flagged rows (expected: none). fp64 scan over all VOC.
// ---------------------------------------------------------------------------
__global__ __launch_bounds__(256)
void fallback_row(const unsigned* __restrict__ flags, const float* __restrict__ q2,
                  const float* __restrict__ codebook, const float* __restrict__ trow,
                  const float* __restrict__ sigrow, float* __restrict__ y)
{
    const int row = blockIdx.x;
    if (!flags[row]) return;

    __shared__ float q2s[DIM];
    __shared__ unsigned long long keys[FCAP];
    __shared__ float wArr[FCAP];
    __shared__ float redf[256];
    __shared__ unsigned redu[256];
    __shared__ unsigned s_cnt;

    const int tid = threadIdx.x;
    for (int i = tid; i < DIM; i += 256) q2s[i] = q2[(size_t)row * DIM + i];
    const float sig = sigrow[row];
    float tf = trow[row] - 0.35f * sig;
    unsigned cnt = 0;

    for (int it = 0; it < 16; it++) {
        if (tid == 0) s_cnt = 0;
        __syncthreads();
        for (int i = tid; i < VOC; i += 256) {
            const float* cb = codebook + (size_t)i * DIM;
            double s = 0.0;
            for (int d = 0; d < DIM; d += 4) {
                float4 c4 = *(const float4*)(cb + d);
                s += (double)q2s[d + 0] * (double)c4.x + (double)q2s[d + 1] * (double)c4.y
                   + (double)q2s[d + 2] * (double)c4.z + (double)q2s[d + 3] * (double)c4.w;
            }
            float vv = (float)s;
            if (vv >= tf) {
                unsigned p = atomicAdd(&s_cnt, 1u);
                if (p < FCAP) {
                    unsigned b = __float_as_uint(vv);
                    unsigned sk = (b & 0x80000000u) ? ~b : (b | 0x80000000u);
                    keys[p] = ((unsigned long long)(~sk) << 32) | (unsigned)i;
                }
            }
        }
        __syncthreads();
        cnt = s_cnt;
        if (cnt > FCAP) { tf += 0.15f * sig; continue; }
        if (cnt < TOPK) { tf -= 0.35f * sig; continue; }
        break;
    }
    if (cnt > FCAP) cnt = FCAP;
    for (int i = tid; i < FCAP; i += 256)
        if (i >= (int)cnt) keys[i] = ~0ULL;
    __syncthreads();

    for (int k = 2; k <= FCAP; k <<= 1) {
        for (int j = k >> 1; j > 0; j >>= 1) {
#pragma unroll
            for (int e = 0; e < 4; e++) {
                int i = tid + e * 256;
                int ixj = i ^ j;
                if (ixj > i) {
                    unsigned long long a = keys[i], b = keys[ixj];
                    if (((i & k) == 0) ? (a > b) : (a < b)) { keys[i] = b; keys[ixj] = a; }
                }
            }
            __syncthreads();
        }
    }

    const unsigned threshInv = (unsigned)(keys[TOPK - 1] >> 32);
    unsigned sk0 = ~(unsigned)(keys[0] >> 32);
    const float vmax = __uint_as_float((sk0 & 0x80000000u) ? (sk0 & 0x7FFFFFFFu) : ~sk0);

    float lsum = 0.f; unsigned lcnt = 0;
    for (int i = tid; i < FCAP; i += 256) {
        unsigned hi = (unsigned)(keys[i] >> 32);
        bool sel = (hi <= threshInv);
        unsigned sk = ~hi;
        float vv = __uint_as_float((sk & 0x80000000u) ? (sk & 0x7FFFFFFFu) : ~sk);
        float w = sel ? expf(vv - vmax) : 0.f;
        wArr[i] = w;
        lsum += w; lcnt += sel ? 1u : 0u;
    }
    redf[tid] = lsum; redu[tid] = lcnt;
    __syncthreads();
    for (int s = 128; s > 0; s >>= 1) {
        if (tid < s) { redf[tid] += redf[tid + s]; redu[tid] += redu[tid + s]; }
        __syncthreads();
    }
    const float invZ = 1.f / redf[0];
    const int selCount = (int)redu[0];

    for (int d = tid; d < DIM; d += 256) {
        float acc = 0.f;
        for (int i = 0; i < selCount; i++) {
            unsigned idx = (unsigned)(keys[i] & 0xFFFFFFFFu);
            acc += wArr[i] * codebook[(size_t)idx * DIM + d];
        }
        y[(size_t)row * DIM + d] = acc * invZ;
    }
}

// ---------------------------------------------------------------------------
extern "C" void kernel_launch(void* const* d_in, const int* in_sizes, int n_in,
                              void* d_out, int out_size, void* d_ws, size_t ws_size,
                              hipStream_t stream)
{
    const float* x        = (const float*)d_in[0];
    const float* codebook = (const float*)d_in[1];
    const float* Wq       = (const float*)d_in[2];
    const float* bq       = (const float*)d_in[3];
    const float* Wk       = (const float*)d_in[4];
    // d_in[5] = bk: per-row-constant shift in dots (top-k & softmax invariant)
    const float* Wv       = (const float*)d_in[6];
    const float* bv       = (const float*)d_in[7];
    float* out = (float*)d_out;

    // workspace (~62 MB)
    float* q2   = (float*)d_ws;                       // 4096x512   (8 MB)
    float* Wqk  = q2   + (size_t)BATCH * DIM;         // 512x512    (1 MB)
    float* bqk  = Wqk  + (size_t)DIM * DIM;           // 512 (pad 1024)
    float* y    = bqk  + 1024;                        // 4096x512   (8 MB)
    float* trow = y    + (size_t)BATCH * DIM;         // 4096
    float* sigr = trow + BATCH;                       // 4096
    unsigned* counters = (unsigned*)(sigr + BATCH);   // 4096
    unsigned* flags    = counters + BATCH;            // 4096
    float* cbarsum     = (float*)(flags + BATCH);     // 512
    unsigned* candBuf  = (unsigned*)(cbarsum + 512);  // 4096x512 (8 MB)
    u16* q2h = (u16*)(candBuf + (size_t)BATCH * CAND_CAP);   // 4 MB
    u16* cbh = q2h + (size_t)BATCH * DIM;                    // 32 MB

    dim3 blk(256);

    // zero counters+flags+cbarsum (contiguous 8704 words)
    zero_ws<<<dim3(34), blk, 0, stream>>>(counters, BATCH * 2 + 512);

    // Wqk = Wq @ Wk^T ; bqk = bq @ Wk^T ; q2 = x @ Wqk + bqk (selection-critical)
    gemm64<true, true><<<dim3(DIM / 64, DIM / 64), blk, 0, stream>>>(
        Wq, Wk, nullptr, Wqk, DIM, DIM, DIM);
    bias_fold<<<dim3(2), blk, 0, stream>>>(bq, Wk, bqk);
    gemm64<false, true><<<dim3(DIM / 64, BATCH / 64), blk, 0, stream>>>(
        x, Wqk, bqk, q2, BATCH, DIM, DIM);

    // analytic per-row candidate threshold
    cbar_accum<<<dim3(VOC / 128), blk, 0, stream>>>(codebook, cbarsum);
    rowstats<<<dim3(BATCH / 4), blk, 0, stream>>>(q2, cbarsum, trow, sigr);

    // pack MFMA operands (bf16 hi only)
    pack_rows<<<dim3(BATCH * 64 / 256), blk, 0, stream>>>(q2, q2h, BATCH, 12);
    pack_rows<<<dim3(VOC * 64 / 256), blk, 0, stream>>>(codebook, cbh, VOC, 15);

    // fused dots GEMM (pipelined, m-fastest order, 3 blocks/CU) + cand append
    mfma_dots<<<dim3(8192), blk, 0, stream>>>(q2h, cbh, trow, candBuf, counters);

    // exact selection + softmax + y = attn @ codebook
    select6<<<dim3(BATCH), blk, 0, stream>>>(
        candBuf, counters, trow, q2, codebook, y, flags);
    fallback_row<<<dim3(BATCH), blk, 0, stream>>>(
        flags, q2, codebook, trow, sigr, y);

    // out = y @ Wv + bv   (linearity: attn @ (cb@Wv+bv) = (attn@cb)@Wv + bv)
    gemm64<false, false><<<dim3(DIM / 64, BATCH / 64), blk, 0, stream>>>(
        y, Wv, bv, out, BATCH, DIM, DIM);
}

// Round 9
// 740.278 us; speedup vs baseline: 1.3903x; 1.0244x over previous
//
#include <hip/hip_runtime.h>
#include <cstdint>

#define VOC   32768
#define DIM   512
#define TOPK  64
#define BATCH 4096

#define KSIG     2.45f
#define EPS_SEL  0.012f
#define CAND_CAP 512
#define RES_CAP  256
#define FCAP     1024

typedef unsigned short u16;
typedef __attribute__((ext_vector_type(8))) short bf16x8;
typedef __attribute__((ext_vector_type(4))) float f32x4;

// ---- bf16 helpers (RNE) ----------------------------------------------------
__device__ __forceinline__ u16 f2bf(float f) {
    unsigned u = __float_as_uint(f);
    unsigned r = (u + 0x7FFFu + ((u >> 16) & 1u)) >> 16;
    return (u16)r;
}
__device__ __forceinline__ float bf2f(u16 h) {
    return __uint_as_float(((unsigned)h) << 16);
}
__device__ __forceinline__ unsigned enc16(u16 h) {
    return (h & 0x8000u) ? (unsigned)((u16)~h) : (unsigned)(h | 0x8000u);
}
__device__ __forceinline__ float dec16(unsigned s16) {
    u16 h = (s16 & 0x8000u) ? (u16)(s16 ^ 0x8000u) : (u16)(~s16);
    return bf2f(h);
}

// ---- async global->LDS 16B -------------------------------------------------
__device__ __forceinline__ void async16(const void* g, void* l) {
    __builtin_amdgcn_global_load_lds(
        (const __attribute__((address_space(1))) void*)g,
        (__attribute__((address_space(3))) void*)l, 16, 0, 0);
}

// ---------------------------------------------------------------------------
// fp32 64x64-tile GEMM + optional per-k-tile fp64 flush. 256 thr, 4x4 micro.
//   BT=false: C = A(MxK) @ B(KxN) (+bias);  BT=true: C = A @ B^T (B NxK)
// ---------------------------------------------------------------------------
template <bool BT, bool F64ACC>
__global__ __launch_bounds__(256)
void gemm64(const float* __restrict__ A, const float* __restrict__ B,
            const float* __restrict__ bias, float* __restrict__ C,
            int M, int N, int K)
{
    const int KS = 16;
    __shared__ float As[KS][68];
    __shared__ float Bs[KS][64];

    const int tid = threadIdx.x;
    const int m0 = blockIdx.y * 64;
    const int n0 = blockIdx.x * 64;
    const int ty = tid >> 4;
    const int tx = tid & 15;

    float acc[4][4];
    double acc64[4][4];
#pragma unroll
    for (int i = 0; i < 4; i++)
#pragma unroll
        for (int j = 0; j < 4; j++) { acc[i][j] = 0.f; if (F64ACC) acc64[i][j] = 0.0; }

    for (int kt = 0; kt < K; kt += KS) {
        {
            int row = tid >> 2, kq = tid & 3;
            const float4 av = *(const float4*)(A + (size_t)(m0 + row) * K + kt + kq * 4);
            As[kq * 4 + 0][row] = av.x;
            As[kq * 4 + 1][row] = av.y;
            As[kq * 4 + 2][row] = av.z;
            As[kq * 4 + 3][row] = av.w;
        }
        if (!BT) {
            int krow = tid >> 4, nq = tid & 15;
            *(float4*)&Bs[krow][nq * 4] =
                *(const float4*)(B + (size_t)(kt + krow) * N + n0 + nq * 4);
        } else {
            int nrow = tid >> 2, kq = tid & 3;
            const float4 bv = *(const float4*)(B + (size_t)(n0 + nrow) * K + kt + kq * 4);
            Bs[kq * 4 + 0][nrow] = bv.x;
            Bs[kq * 4 + 1][nrow] = bv.y;
            Bs[kq * 4 + 2][nrow] = bv.z;
            Bs[kq * 4 + 3][nrow] = bv.w;
        }
        __syncthreads();

#pragma unroll
        for (int kk = 0; kk < KS; kk++) {
            float4 a = *(const float4*)&As[kk][ty * 4];
            float4 b = *(const float4*)&Bs[kk][tx * 4];
            float av[4] = {a.x, a.y, a.z, a.w};
            float bv[4] = {b.x, b.y, b.z, b.w};
#pragma unroll
            for (int i = 0; i < 4; i++)
#pragma unroll
                for (int j = 0; j < 4; j++)
                    acc[i][j] += av[i] * bv[j];
        }
        __syncthreads();
        if (F64ACC) {
#pragma unroll
            for (int i = 0; i < 4; i++)
#pragma unroll
                for (int j = 0; j < 4; j++) { acc64[i][j] += (double)acc[i][j]; acc[i][j] = 0.f; }
        }
    }

    float4 bb = make_float4(0.f, 0.f, 0.f, 0.f);
    if (bias) bb = *(const float4*)(bias + n0 + tx * 4);
#pragma unroll
    for (int i = 0; i < 4; i++) {
        float4 o;
        o.x = (F64ACC ? (float)acc64[i][0] : acc[i][0]) + bb.x;
        o.y = (F64ACC ? (float)acc64[i][1] : acc[i][1]) + bb.y;
        o.z = (F64ACC ? (float)acc64[i][2] : acc[i][2]) + bb.z;
        o.w = (F64ACC ? (float)acc64[i][3] : acc[i][3]) + bb.w;
        *(float4*)(C + (size_t)(m0 + ty * 4 + i) * N + n0 + tx * 4) = o;
    }
}

// ---------------------------------------------------------------------------
__global__ void bias_fold(const float* __restrict__ bq, const float* __restrict__ Wk,
                          float* __restrict__ bqk)
{
    int j = blockIdx.x * 256 + threadIdx.x;
    if (j >= DIM) return;
    double s = 0.0;
    const float* wr = Wk + (size_t)j * DIM;
    for (int d = 0; d < DIM; d++) s += (double)bq[d] * (double)wr[d];
    bqk[j] = (float)s;
}

__global__ void zero_ws(unsigned* __restrict__ p, int n)
{
    int i = blockIdx.x * 256 + threadIdx.x;
    if (i < n) p[i] = 0u;
}

// ---------------------------------------------------------------------------
// Column sums of codebook (for mu_row). 256 blocks x 128 rows.
// ---------------------------------------------------------------------------
__global__ __launch_bounds__(256)
void cbar_accum(const float* __restrict__ cb, float* __restrict__ cbarsum)
{
    const int tid = threadIdx.x;
    const int r0 = blockIdx.x * 128;
    float s0 = 0.f, s1 = 0.f;
    for (int r = 0; r < 128; r++) {
        const float* rp = cb + (size_t)(r0 + r) * DIM;
        s0 += rp[tid];
        s1 += rp[tid + 256];
    }
    atomicAdd(&cbarsum[tid], s0);
    atomicAdd(&cbarsum[tid + 256], s1);
}

// ---------------------------------------------------------------------------
// Per-row analytic threshold: t = mu + KSIG*sigma, sigma = ||q2_row||/sqrt(1536).
// ---------------------------------------------------------------------------
__global__ __launch_bounds__(256)
void rowstats(const float* __restrict__ q2, const float* __restrict__ cbarsum,
              float* __restrict__ trow, float* __restrict__ sigrow)
{
    const int tid = threadIdx.x, lane = tid & 63, wave = tid >> 6;
    const int row = blockIdx.x * 4 + wave;
    const float* qp = q2 + (size_t)row * DIM + lane * 8;
    float4 a0 = *(const float4*)qp, a1 = *(const float4*)(qp + 4);
    const float* cp = cbarsum + lane * 8;
    float4 c0 = *(const float4*)cp, c1 = *(const float4*)(cp + 4);
    float mu = a0.x*c0.x + a0.y*c0.y + a0.z*c0.z + a0.w*c0.w
             + a1.x*c1.x + a1.y*c1.y + a1.z*c1.z + a1.w*c1.w;
    float nr = a0.x*a0.x + a0.y*a0.y + a0.z*a0.z + a0.w*a0.w
             + a1.x*a1.x + a1.y*a1.y + a1.z*a1.z + a1.w*a1.w;
#pragma unroll
    for (int off = 32; off > 0; off >>= 1) {
        mu += __shfl_down(mu, off);
        nr += __shfl_down(nr, off);
    }
    if (lane == 0) {
        mu *= (1.f / VOC);
        float sig = sqrtf(nr * (1.f / 1536.f));
        trow[row] = mu + KSIG * sig;
        sigrow[row] = sig;
    }
}

// ---------------------------------------------------------------------------
// Pack fp32 [R x 512] -> MFMA operand layout pk[ks][ch][R][8] bf16 (+opt lo).
// ---------------------------------------------------------------------------
__global__ __launch_bounds__(256)
void pack_rows(const float* __restrict__ src, u16* __restrict__ hi,
               u16* __restrict__ lo, int R, int log2R)
{
    int idx = blockIdx.x * 256 + threadIdx.x;
    int c8  = idx >> log2R;
    int row = idx & (R - 1);
    const float* sp = src + (size_t)row * DIM + c8 * 8;
    float xv[8];
    *(float4*)&xv[0] = *(const float4*)sp;
    *(float4*)&xv[4] = *(const float4*)(sp + 4);
    int ks = c8 >> 2, ch = c8 & 3;
    size_t ob = ((size_t)(ks * 4 + ch) * R + row) * 8;
    u16 h[8], l[8];
#pragma unroll
    for (int j = 0; j < 8; j++) {
        h[j] = f2bf(xv[j]);
        l[j] = f2bf(xv[j] - bf2f(h[j]));
    }
    *(uint4*)(hi + ob) = *(const uint4*)h;
    if (lo) *(uint4*)(lo + ob) = *(const uint4*)l;
}

// ---------------------------------------------------------------------------
// Pack W (B-operand: B[k][n], 512x512) -> pk[ks][ch][512(n)][8(k)] hi+lo
// ---------------------------------------------------------------------------
__global__ __launch_bounds__(256)
void pack_bT(const float* __restrict__ W, u16* __restrict__ hi, u16* __restrict__ lo)
{
    int idx = blockIdx.x * 256 + threadIdx.x;
    int n  = idx & (DIM - 1);
    int c8 = idx >> 9;
    int ks = c8 >> 2, ch = c8 & 3;
    size_t ob = ((size_t)(ks * 4 + ch) * DIM + n) * 8;
    u16 h[8], l[8];
#pragma unroll
    for (int j = 0; j < 8; j++) {
        float x = W[(size_t)(c8 * 8 + j) * DIM + n];
        h[j] = f2bf(x);
        l[j] = f2bf(x - bf2f(h[j]));
    }
    *(uint4*)(hi + ob) = *(const uint4*)h;
    *(uint4*)(lo + ob) = *(const uint4*)l;
}

// ---------------------------------------------------------------------------
// Fused dots GEMM v5: 3-stage pipeline (vmcnt(4) keeps next stage's loads in
// flight across the raw barrier) + XCD-AFFINITY BANDING: block L -> xcd=L&7
// (empirical round-robin; any mapping stays correct), XCD x owns m-tiles
// [4x,4x+4). Per-XCD L2 set = q2h slice 512KB + cbh n-window ~2MB << 4MB L2,
// so staging hits L2 instead of thrashing to L3 (round-8 stall).
// Epilogue appends candidates (>= trow[row]).
// ---------------------------------------------------------------------------
__global__ __launch_bounds__(256, 3)
void mfma_dots(const u16* __restrict__ Ah, const u16* __restrict__ Bh,
               const float* __restrict__ trow, unsigned* __restrict__ candBuf,
               unsigned* __restrict__ counters)
{
    __shared__ u16 lds[3 * 8192];      // 3 stages x (A 4096 + B 4096) u16

    const int tid  = threadIdx.x;
    const int lane = tid & 63;
    const int wave = tid >> 6;
    const int wm = wave >> 1, wn = wave & 1;
    const int lr = lane & 15;
    const int q  = lane >> 4;

    // XCD-affinity: xcd owns a 4-m-tile band; within XCD, m fastest then n.
    const int L   = blockIdx.x;
    const int xcd = L & 7;
    const int j   = L >> 3;                    // 0..1023
    const int m0  = (xcd * 4 + (j & 3)) * 128;
    const int n0  = (j >> 2) * 128;

    const int a  = wave >> 1;                  // 0: stage A (q2h), 1: stage B (cbh)
    const u16* src = a ? Bh : Ah;
    const int rb   = a ? n0 : m0;
    const size_t R = a ? (size_t)VOC : (size_t)BATCH;
    const int i0   = (wave & 1) * 4;

    f32x4 acc[4][4] = {};

#define ISSUE(ks, b)                                                          \
    {                                                                         \
        _Pragma("unroll")                                                     \
        for (int s_ = 0; s_ < 4; s_++) {                                      \
            int i_ = i0 + s_;                                                 \
            const u16* gp_ = src + ((size_t)((ks) * 4 + (i_ >> 1)) * R + rb   \
                                    + (i_ & 1) * 64 + lane) * 8;              \
            async16(gp_, &lds[(b) * 8192 + a * 4096 + i_ * 512 + lane * 8]);  \
        }                                                                     \
    }

    ISSUE(0, 0)
    ISSUE(1, 1)

    for (int s = 0; s < 16; s++) {
        if (s == 15) __builtin_amdgcn_s_waitcnt(0x0F70);   // vmcnt(0)
        else         __builtin_amdgcn_s_waitcnt(0x0F74);   // vmcnt(4)
        __builtin_amdgcn_s_barrier();
        if (s < 14) {
            int b2 = (s + 2) % 3;
            ISSUE(s + 2, b2)
        }
        const u16* base = &lds[(s % 3) * 8192];

        bf16x8 ah[4];
#pragma unroll
        for (int mt = 0; mt < 4; mt++)
            ah[mt] = *(const bf16x8*)&base[q * 1024 + (wm * 64 + mt * 16 + lr) * 8];
#pragma unroll
        for (int nt = 0; nt < 4; nt++) {
            bf16x8 bh = *(const bf16x8*)&base[4096 + q * 1024 + (wn * 64 + nt * 16 + lr) * 8];
#pragma unroll
            for (int mt = 0; mt < 4; mt++)
                acc[mt][nt] = __builtin_amdgcn_mfma_f32_16x16x32_bf16(ah[mt], bh, acc[mt][nt], 0, 0, 0);
        }
    }
#undef ISSUE

    // epilogue: threshold-append candidates
#pragma unroll
    for (int mt = 0; mt < 4; mt++) {
#pragma unroll
        for (int r = 0; r < 4; r++) {
            int rowg = m0 + wm * 64 + mt * 16 + q * 4 + r;
            float tr = trow[rowg];
#pragma unroll
            for (int nt = 0; nt < 4; nt++) {
                float val = acc[mt][nt][r];
                if (val >= tr) {
                    unsigned slot = atomicAdd(&counters[rowg], 1u);
                    if (slot < CAND_CAP) {
                        unsigned s16 = enc16(f2bf(val));
                        candBuf[(size_t)rowg * CAND_CAP + slot] =
                            (s16 << 16) | (unsigned)(n0 + wn * 64 + nt * 16 + lr);
                    }
                }
            }
        }
    }
}

// ---------------------------------------------------------------------------
// out = A @ W + bias in bf16 hi/lo 3-pass MFMA (error ~1e-6). A packed hi/lo
// [ks][ch][Ma][8]; W packed hi/lo [ks][ch][512n][8k]. 2-stage double buffer.
// ---------------------------------------------------------------------------
__global__ __launch_bounds__(256, 2)
void mfma_out(const u16* __restrict__ Ah, const u16* __restrict__ Al,
              const u16* __restrict__ Bh, const u16* __restrict__ Bl,
              const float* __restrict__ bias, float* __restrict__ Cout, int Ma)
{
    __shared__ u16 lds[2 * 16384];   // 2 stages x 4 arrays x 4096 u16 (64 KB)

    const int tid  = threadIdx.x;
    const int lane = tid & 63;
    const int wave = tid >> 6;
    const int wm = wave >> 1, wn = wave & 1;
    const int m0 = blockIdx.y * 128, n0 = blockIdx.x * 128;
    const int lr = lane & 15;
    const int q  = lane >> 4;

    f32x4 acc[4][4] = {};
    const u16* garr[4] = {Ah, Bh, Al, Bl};
    const int a = wave;                       // one array per wave
    const u16* src = garr[a];
    const bool isA = (a == 0 || a == 2);
    const int rb = isA ? m0 : n0;
    const size_t R = isA ? (size_t)Ma : (size_t)DIM;

#define VISSUE(ks, b)                                                         \
    {                                                                         \
        _Pragma("unroll")                                                     \
        for (int i_ = 0; i_ < 8; i_++) {                                      \
            const u16* gp_ = src + ((size_t)((ks) * 4 + (i_ >> 1)) * R + rb   \
                                    + (i_ & 1) * 64 + lane) * 8;              \
            async16(gp_, &lds[(b) * 16384 + a * 4096 + i_ * 512 + lane * 8]); \
        }                                                                     \
    }

    VISSUE(0, 0)

    for (int ks = 0; ks < 16; ks++) {
        __syncthreads();                       // drains vmcnt(0): stage ks in LDS
        if (ks < 15) VISSUE(ks + 1, (ks + 1) & 1)
        const u16* base = &lds[(ks & 1) * 16384];

        bf16x8 ah[4], al[4];
#pragma unroll
        for (int mt = 0; mt < 4; mt++) {
            int row = wm * 64 + mt * 16 + lr;
            ah[mt] = *(const bf16x8*)&base[0 * 4096 + q * 1024 + row * 8];
            al[mt] = *(const bf16x8*)&base[2 * 4096 + q * 1024 + row * 8];
        }
#pragma unroll
        for (int nt = 0; nt < 4; nt++) {
            int col = wn * 64 + nt * 16 + lr;
            bf16x8 bh = *(const bf16x8*)&base[1 * 4096 + q * 1024 + col * 8];
            bf16x8 bl = *(const bf16x8*)&base[3 * 4096 + q * 1024 + col * 8];
#pragma unroll
            for (int mt = 0; mt < 4; mt++) {
                acc[mt][nt] = __builtin_amdgcn_mfma_f32_16x16x32_bf16(ah[mt], bh, acc[mt][nt], 0, 0, 0);
                acc[mt][nt] = __builtin_amdgcn_mfma_f32_16x16x32_bf16(ah[mt], bl, acc[mt][nt], 0, 0, 0);
                acc[mt][nt] = __builtin_amdgcn_mfma_f32_16x16x32_bf16(al[mt], bh, acc[mt][nt], 0, 0, 0);
            }
        }
    }
#undef VISSUE

#pragma unroll
    for (int mt = 0; mt < 4; mt++)
#pragma unroll
        for (int nt = 0; nt < 4; nt++) {
            int col = n0 + wn * 64 + nt * 16 + lr;
            float bb = bias[col];
#pragma unroll
            for (int r = 0; r < 4; r++) {
                int rowg = m0 + wm * 64 + mt * 16 + q * 4 + r;
                Cout[(size_t)rowg * DIM + col] = acc[mt][nt][r] + bb;
            }
        }
}

// ---------------------------------------------------------------------------
// Select v6: sort candidates by approx -> verify t <= a64 - 2*EPS (proof of
// top-64 coverage) -> fp64 rescue of band -> exact sort -> thresh (ties) ->
// softmax -> y_row = sum w_i * codebook[idx_i] (rows L2-hot from the rescue).
// ---------------------------------------------------------------------------
__global__ __launch_bounds__(256)
void select6(const unsigned* __restrict__ candBuf, const unsigned* __restrict__ counters,
             const float* __restrict__ trow, const float* __restrict__ q2,
             const float* __restrict__ codebook, float* __restrict__ y,
             unsigned* __restrict__ flags)
{
    __shared__ unsigned recs[CAND_CAP];
    __shared__ unsigned long long keys[RES_CAP];
    __shared__ float q2s[DIM];
    __shared__ float wArr[RES_CAP];
    __shared__ float redf[256];
    __shared__ unsigned redu[256];
    __shared__ unsigned s_R;

    const int tid  = threadIdx.x;
    const int lane = tid & 63;
    const int wave = tid >> 6;
    const int row  = blockIdx.x;

    const unsigned cnt = counters[row];
    if (cnt < TOPK || cnt > CAND_CAP) {
        if (tid == 0) flags[row] = 1u;
        return;
    }
    for (int i = tid; i < DIM; i += 256) q2s[i] = q2[(size_t)row * DIM + i];
    for (int i = tid; i < CAND_CAP; i += 256)
        recs[i] = (i < (int)cnt) ? candBuf[(size_t)row * CAND_CAP + i] : 0u;
    if (tid == 0) s_R = 0;
    __syncthreads();

    // bitonic sort 512 u32 DESCENDING (sortkey high 16 bits; pads=0 last)
    for (int k = 2; k <= CAND_CAP; k <<= 1) {
        for (int j = k >> 1; j > 0; j >>= 1) {
#pragma unroll
            for (int e = 0; e < 2; e++) {
                int i = tid + e * 256;
                int ixj = i ^ j;
                if (ixj > i) {
                    unsigned a = recs[i], b = recs[ixj];
                    if (((i & k) == 0) ? (a < b) : (a > b)) { recs[i] = b; recs[ixj] = a; }
                }
            }
            __syncthreads();
        }
    }

    const float a64  = dec16(recs[TOPK - 1] >> 16);
    const float band = a64 - 2.f * EPS_SEL;
    if (trow[row] > band) {
        if (tid == 0) flags[row] = 1u;
        return;
    }

#pragma unroll
    for (int e = 0; e < 2; e++) {
        int i = tid + e * 256;
        if (i < (int)cnt && dec16(recs[i] >> 16) >= band) atomicAdd(&s_R, 1u);
    }
    __syncthreads();
    const int R = (int)s_R;
    if (R > RES_CAP) {
        if (tid == 0) flags[row] = 1u;
        return;
    }

    // fp64 rescue: wave per candidate, coalesced codebook reads
    for (int c = wave; c < R; c += 4) {
        unsigned idx = recs[c] & 0xFFFFu;
        const float* cb = codebook + (size_t)idx * DIM + lane * 8;
        float4 c0 = *(const float4*)cb, c1 = *(const float4*)(cb + 4);
        const float* qp = &q2s[lane * 8];
        float4 a0 = *(const float4*)qp, a1 = *(const float4*)(qp + 4);
        double s = (double)a0.x * c0.x + (double)a0.y * c0.y
                 + (double)a0.z * c0.z + (double)a0.w * c0.w
                 + (double)a1.x * c1.x + (double)a1.y * c1.y
                 + (double)a1.z * c1.z + (double)a1.w * c1.w;
#pragma unroll
        for (int off = 32; off > 0; off >>= 1) s += __shfl_down(s, off);
        if (lane == 0) {
            float val = (float)s;
            unsigned b = __float_as_uint(val);
            unsigned sk = (b & 0x80000000u) ? ~b : (b | 0x80000000u);
            keys[c] = ((unsigned long long)(~sk) << 32) | idx;
        }
    }
    if (tid >= R && tid < RES_CAP) keys[tid] = ~0ULL;
    __syncthreads();

    // bitonic sort 256 u64 ascending (= descending by exact value)
    for (int k = 2; k <= RES_CAP; k <<= 1) {
        for (int j = k >> 1; j > 0; j >>= 1) {
            int ixj = tid ^ j;
            if (ixj > tid) {
                unsigned long long a = keys[tid], b2 = keys[ixj];
                if (((tid & k) == 0) ? (a > b2) : (a < b2)) { keys[tid] = b2; keys[ixj] = a; }
            }
            __syncthreads();
        }
    }

    const unsigned threshInv = (unsigned)(keys[TOPK - 1] >> 32);
    unsigned sk0 = ~(unsigned)(keys[0] >> 32);
    const float vmax = __uint_as_float((sk0 & 0x80000000u) ? (sk0 & 0x7FFFFFFFu) : ~sk0);

    unsigned hi = (unsigned)(keys[tid] >> 32);
    bool sel = (hi <= threshInv);
    unsigned sk = ~hi;
    float val = __uint_as_float((sk & 0x80000000u) ? (sk & 0x7FFFFFFFu) : ~sk);
    float w = sel ? expf(val - vmax) : 0.f;
    wArr[tid] = w;
    redf[tid] = w;
    redu[tid] = sel ? 1u : 0u;
    __syncthreads();
    for (int s = 128; s > 0; s >>= 1) {
        if (tid < s) { redf[tid] += redf[tid + s]; redu[tid] += redu[tid + s]; }
        __syncthreads();
    }
    const float invZ = 1.0f / redf[0];
    const int selCount = (int)redu[0];

    // y_row = sum_i w_i * codebook[idx_i, :]
    for (int d = tid; d < DIM; d += 256) {
        float acc = 0.f;
        for (int i = 0; i < selCount; i++) {
            unsigned idx = (unsigned)(keys[i] & 0xFFFFFFFFu);
            acc += wArr[i] * codebook[(size_t)idx * DIM + d];
        }
        y[(size_t)row * DIM + d] = acc * invZ;
    }
}

// ---------------------------------------------------------------------------
// Exact fallback for flagged rows (expected: none). fp64 scan over all VOC.
// ---------------------------------------------------------------------------
__global__ __launch_bounds__(256)
void fallback_row(const unsigned* __restrict__ flags, const float* __restrict__ q2,
                  const float* __restrict__ codebook, const float* __restrict__ trow,
                  const float* __restrict__ sigrow, float* __restrict__ y)
{
    const int row = blockIdx.x;
    if (!flags[row]) return;

    __shared__ float q2s[DIM];
    __shared__ unsigned long long keys[FCAP];
    __shared__ float wArr[FCAP];
    __shared__ float redf[256];
    __shared__ unsigned redu[256];
    __shared__ unsigned s_cnt;

    const int tid = threadIdx.x;
    for (int i = tid; i < DIM; i += 256) q2s[i] = q2[(size_t)row * DIM + i];
    const float sig = sigrow[row];
    float tf = trow[row] - 0.35f * sig;
    unsigned cnt = 0;

    for (int it = 0; it < 16; it++) {
        if (tid == 0) s_cnt = 0;
        __syncthreads();
        for (int i = tid; i < VOC; i += 256) {
            const float* cb = codebook + (size_t)i * DIM;
            double s = 0.0;
            for (int d = 0; d < DIM; d += 4) {
                float4 c4 = *(const float4*)(cb + d);
                s += (double)q2s[d + 0] * (double)c4.x + (double)q2s[d + 1] * (double)c4.y
                   + (double)q2s[d + 2] * (double)c4.z + (double)q2s[d + 3] * (double)c4.w;
            }
            float vv = (float)s;
            if (vv >= tf) {
                unsigned p = atomicAdd(&s_cnt, 1u);
                if (p < FCAP) {
                    unsigned b = __float_as_uint(vv);
                    unsigned sk = (b & 0x80000000u) ? ~b : (b | 0x80000000u);
                    keys[p] = ((unsigned long long)(~sk) << 32) | (unsigned)i;
                }
            }
        }
        __syncthreads();
        cnt = s_cnt;
        if (cnt > FCAP) { tf += 0.15f * sig; continue; }
        if (cnt < TOPK) { tf -= 0.35f * sig; continue; }
        break;
    }
    if (cnt > FCAP) cnt = FCAP;
    for (int i = tid; i < FCAP; i += 256)
        if (i >= (int)cnt) keys[i] = ~0ULL;
    __syncthreads();

    for (int k = 2; k <= FCAP; k <<= 1) {
        for (int j = k >> 1; j > 0; j >>= 1) {
#pragma unroll
            for (int e = 0; e < 4; e++) {
                int i = tid + e * 256;
                int ixj = i ^ j;
                if (ixj > i) {
                    unsigned long long a = keys[i], b = keys[ixj];
                    if (((i & k) == 0) ? (a > b) : (a < b)) { keys[i] = b; keys[ixj] = a; }
                }
            }
            __syncthreads();
        }
    }

    const unsigned threshInv = (unsigned)(keys[TOPK - 1] >> 32);
    unsigned sk0 = ~(unsigned)(keys[0] >> 32);
    const float vmax = __uint_as_float((sk0 & 0x80000000u) ? (sk0 & 0x7FFFFFFFu) : ~sk0);

    float lsum = 0.f; unsigned lcnt = 0;
    for (int i = tid; i < FCAP; i += 256) {
        unsigned hi = (unsigned)(keys[i] >> 32);
        bool sel = (hi <= threshInv);
        unsigned sk = ~hi;
        float vv = __uint_as_float((sk & 0x80000000u) ? (sk & 0x7FFFFFFFu) : ~sk);
        float w = sel ? expf(vv - vmax) : 0.f;
        wArr[i] = w;
        lsum += w; lcnt += sel ? 1u : 0u;
    }
    redf[tid] = lsum; redu[tid] = lcnt;
    __syncthreads();
    for (int s = 128; s > 0; s >>= 1) {
        if (tid < s) { redf[tid] += redf[tid + s]; redu[tid] += redu[tid + s]; }
        __syncthreads();
    }
    const float invZ = 1.f / redf[0];
    const int selCount = (int)redu[0];

    for (int d = tid; d < DIM; d += 256) {
        float acc = 0.f;
        for (int i = 0; i < selCount; i++) {
            unsigned idx = (unsigned)(keys[i] & 0xFFFFFFFFu);
            acc += wArr[i] * codebook[(size_t)idx * DIM + d];
        }
        y[(size_t)row * DIM + d] = acc * invZ;
    }
}

// ---------------------------------------------------------------------------
extern "C" void kernel_launch(void* const* d_in, const int* in_sizes, int n_in,
                              void* d_out, int out_size, void* d_ws, size_t ws_size,
                              hipStream_t stream)
{
    const float* x        = (const float*)d_in[0];
    const float* codebook = (const float*)d_in[1];
    const float* Wq       = (const float*)d_in[2];
    const float* bq       = (const float*)d_in[3];
    const float* Wk       = (const float*)d_in[4];
    // d_in[5] = bk: per-row-constant shift in dots (top-k & softmax invariant)
    const float* Wv       = (const float*)d_in[6];
    const float* bv       = (const float*)d_in[7];
    float* out = (float*)d_out;

    // workspace (~72 MB)
    float* q2   = (float*)d_ws;                       // 4096x512   (8 MB)
    float* Wqk  = q2   + (size_t)BATCH * DIM;         // 512x512    (1 MB)
    float* bqk  = Wqk  + (size_t)DIM * DIM;           // 512 (pad 1024)
    float* y    = bqk  + 1024;                        // 4096x512   (8 MB)
    float* trow = y    + (size_t)BATCH * DIM;         // 4096
    float* sigr = trow + BATCH;                       // 4096
    unsigned* counters = (unsigned*)(sigr + BATCH);   // 4096
    unsigned* flags    = counters + BATCH;            // 4096
    float* cbarsum     = (float*)(flags + BATCH);     // 512
    unsigned* candBuf  = (unsigned*)(cbarsum + 512);  // 4096x512 (8 MB)
    u16* q2h = (u16*)(candBuf + (size_t)BATCH * CAND_CAP);   // 4 MB
    u16* cbh = q2h + (size_t)BATCH * DIM;                    // 32 MB
    u16* yh  = cbh + (size_t)VOC * DIM;                      // 4 MB
    u16* yl  = yh  + (size_t)BATCH * DIM;                    // 4 MB
    u16* wvh = yl  + (size_t)BATCH * DIM;                    // 0.5 MB
    u16* wvl = wvh + (size_t)DIM * DIM;                      // 0.5 MB

    dim3 blk(256);

    // zero counters+flags+cbarsum (contiguous 8704 words)
    zero_ws<<<dim3(34), blk, 0, stream>>>(counters, BATCH * 2 + 512);

    // Wqk = Wq @ Wk^T ; bqk = bq @ Wk^T ; q2 = x @ Wqk + bqk (selection-critical)
    gemm64<true, true><<<dim3(DIM / 64, DIM / 64), blk, 0, stream>>>(
        Wq, Wk, nullptr, Wqk, DIM, DIM, DIM);
    bias_fold<<<dim3(2), blk, 0, stream>>>(bq, Wk, bqk);
    gemm64<false, true><<<dim3(DIM / 64, BATCH / 64), blk, 0, stream>>>(
        x, Wqk, bqk, q2, BATCH, DIM, DIM);

    // analytic per-row candidate threshold
    cbar_accum<<<dim3(VOC / 128), blk, 0, stream>>>(codebook, cbarsum);
    rowstats<<<dim3(BATCH / 4), blk, 0, stream>>>(q2, cbarsum, trow, sigr);

    // pack MFMA operands
    pack_rows<<<dim3(BATCH * 64 / 256), blk, 0, stream>>>(q2, q2h, nullptr, BATCH, 12);
    pack_rows<<<dim3(VOC * 64 / 256), blk, 0, stream>>>(codebook, cbh, nullptr, VOC, 15);
    pack_bT<<<dim3(DIM * 64 / 256), blk, 0, stream>>>(Wv, wvh, wvl);

    // fused dots GEMM (pipelined, XCD-affinity banding) + candidate append
    mfma_dots<<<dim3(8192), blk, 0, stream>>>(q2h, cbh, trow, candBuf, counters);

    // exact selection + softmax + y = attn @ codebook
    select6<<<dim3(BATCH), blk, 0, stream>>>(
        candBuf, counters, trow, q2, codebook, y, flags);
    fallback_row<<<dim3(BATCH), blk, 0, stream>>>(
        flags, q2, codebook, trow, sigr, y);

    // out = y @ Wv + bv  (hi/lo 3-pass MFMA; linearity: sum w = 1)
    pack_rows<<<dim3(BATCH * 64 / 256), blk, 0, stream>>>(y, yh, yl, BATCH, 12);
    mfma_out<<<dim3(DIM / 128, BATCH / 128), blk, 0, stream>>>(
        yh, yl, wvh, wvl, bv, out, BATCH);
}